// Round 13
// baseline (448.309 us; speedup 1.0000x reference)
//
#include <hip/hip_runtime.h>
#include <math.h>

// Problem constants (fixed by the reference)
constexpr int N  = 64000;
constexpr int E  = 1024000;
constexpr int D  = 512;
constexpr int KT = 2048;
constexpr int B  = 16;
constexpr int NP = 4000;   // nodes per graph
constexpr int KP = 128;    // clusters per graph
constexpr int NR = N / 256;        // 250 dst-ranges of 256 nodes
constexpr int EPB = 2048;          // edges per split block
constexpr int NPB = E / EPB;       // 500 split blocks
constexpr int RSTRIDE = 4608;      // padded bin stride (Poisson 4096 +8 sigma)
constexpr int BSTRIDE = 4608;      // padded bucket stride (Poisson 4000 +9.6 sigma)

typedef __attribute__((ext_vector_type(4))) float f32x4;
typedef __attribute__((ext_vector_type(2))) float f32x2;
typedef __attribute__((ext_vector_type(8))) short bf16x8;   // MFMA A/B frag (8 bf16)
typedef __attribute__((ext_vector_type(8))) unsigned short u16x8;

__device__ __forceinline__ unsigned short f2bf(float f) {
    unsigned u = __builtin_bit_cast(unsigned, f);
    return (unsigned short)((u + 0x7FFFu + ((u >> 16) & 1u)) >> 16);
}
__device__ __forceinline__ float bf2f(unsigned short h) {
    unsigned u = (unsigned)h << 16;
    return __builtin_bit_cast(float, u);
}

// ---- fp8 e4m3 (OCP) encode/decode: HW pk-cvt if available, bit-exact fallback ----
__device__ __forceinline__ unsigned char f2fp8_sw(float f) {
    unsigned u = __builtin_bit_cast(unsigned, f);
    unsigned s = u >> 31;
    float a = fabsf(f);
    if (a > 448.f) a = 448.f;
    unsigned code;
    if (a < 0.015625f) {
        code = (unsigned)rintf(a * 512.0f);
    } else {
        unsigned au = __builtin_bit_cast(unsigned, a);
        unsigned mant = au & 0x7FFFFFu;
        unsigned rnd = 0x7FFFFu + ((mant >> 20) & 1u);
        unsigned r2 = au + rnd;
        int e = (int)(r2 >> 23) - 127;
        unsigned m3 = (r2 >> 20) & 7u;
        if (e > 8) { e = 8; m3 = 7; }
        code = (unsigned)((e + 7) << 3) | m3;
    }
    return (unsigned char)(code | (s << 7));
}
__device__ __forceinline__ float fp82f_sw(unsigned b) {
    unsigned s = b >> 7, e = (b >> 3) & 15u, m = b & 7u;
    float vn = __builtin_bit_cast(float, ((e + 120u) << 23) | (m << 20));
    float vs = (float)(int)m * 0x1p-9f;
    float v = e ? vn : vs;
    return s ? -v : v;
}

__device__ __forceinline__ unsigned char f2fp8(float f) {
#if __has_builtin(__builtin_amdgcn_cvt_pk_fp8_f32)
    int w = __builtin_amdgcn_cvt_pk_fp8_f32(f, 0.f, 0, false);
    return (unsigned char)(w & 0xFF);
#else
    return f2fp8_sw(f);
#endif
}

__device__ __forceinline__ unsigned pack4_fp8(float f0, float f1, float f2, float f3) {
#if __has_builtin(__builtin_amdgcn_cvt_pk_fp8_f32)
    int w = __builtin_amdgcn_cvt_pk_fp8_f32(f0, f1, 0, false);
    w = __builtin_amdgcn_cvt_pk_fp8_f32(f2, f3, w, true);
    return (unsigned)w;
#else
    return (unsigned)f2fp8_sw(f0) | ((unsigned)f2fp8_sw(f1) << 8) |
           ((unsigned)f2fp8_sw(f2) << 16) | ((unsigned)f2fp8_sw(f3) << 24);
#endif
}

__device__ __forceinline__ void acc8_fp8(float* a, uint2 w) {
#if __has_builtin(__builtin_amdgcn_cvt_pk_f32_fp8)
    f32x2 p0 = __builtin_amdgcn_cvt_pk_f32_fp8((int)w.x, false);
    f32x2 p1 = __builtin_amdgcn_cvt_pk_f32_fp8((int)w.x, true);
    f32x2 p2 = __builtin_amdgcn_cvt_pk_f32_fp8((int)w.y, false);
    f32x2 p3 = __builtin_amdgcn_cvt_pk_f32_fp8((int)w.y, true);
    a[0] += p0.x; a[1] += p0.y; a[2] += p1.x; a[3] += p1.y;
    a[4] += p2.x; a[5] += p2.y; a[6] += p3.x; a[7] += p3.y;
#else
    #pragma unroll
    for (int q = 0; q < 4; ++q) a[q] += fp82f_sw((w.x >> (8 * q)) & 255u);
    #pragma unroll
    for (int q = 0; q < 4; ++q) a[4 + q] += fp82f_sw((w.y >> (8 * q)) & 255u);
#endif
}

// async global->LDS, 16B per lane; lds dest must be wave-uniform base
typedef const __attribute__((address_space(1))) unsigned int* gas_u32p;
typedef __attribute__((address_space(3))) unsigned int* las_u32p;
__device__ __forceinline__ void glds16(const unsigned short* g, unsigned short* l) {
    __builtin_amdgcn_global_load_lds((gas_u32p)(const void*)g, (las_u32p)(void*)l, 16, 0, 0);
}

// block-wide (256 thr) inclusive scan; ws is 4-int LDS scratch
__device__ __forceinline__ int block_incl_scan(int v, int* ws) {
    int t = threadIdx.x, lane = t & 63, w = t >> 6;
    int x = v;
    #pragma unroll
    for (int off = 1; off < 64; off <<= 1) {
        int y = __shfl_up(x, off);
        if (lane >= off) x += y;
    }
    if (lane == 63) ws[w] = x;
    __syncthreads();
    if (t < 4) {
        int s = ws[t];
        #pragma unroll
        for (int off = 1; off < 4; off <<= 1) {
            int y = __shfl_up(s, off);
            if (t >= off) s += y;
        }
        ws[t] = s;
    }
    __syncthreads();
    return x + (w > 0 ? ws[w - 1] : 0);
}

// ---------------------------------------------------------------------------
// f32 -> bf16 + fp8 dual convert (n multiple of 8)
// ---------------------------------------------------------------------------
__global__ __launch_bounds__(256) void k_cvt(const float* __restrict__ in,
                                             unsigned short* __restrict__ outb,
                                             unsigned char* __restrict__ out8,
                                             long long n) {
    long long i = ((long long)blockIdx.x * 256 + threadIdx.x) * 8;
    if (i >= n) return;
    f32x4 a = *(const f32x4*)&in[i];
    f32x4 b = *(const f32x4*)&in[i + 4];
    u16x8 o;
    o[0] = f2bf(a.x); o[1] = f2bf(a.y); o[2] = f2bf(a.z); o[3] = f2bf(a.w);
    o[4] = f2bf(b.x); o[5] = f2bf(b.y); o[6] = f2bf(b.z); o[7] = f2bf(b.w);
    *(u16x8*)&outb[i] = o;
    uint2 w;
    w.x = pack4_fp8(a.x, a.y, a.z, a.w);
    w.y = pack4_fp8(b.x, b.y, b.z, b.w);
    *(uint2*)&out8[i] = w;
}

// zero the pad rows (row index N) of fb, scb, hfb, f8b, sc8 each launch
__global__ void k_zrow(unsigned short* __restrict__ fb,
                       unsigned short* __restrict__ scb,
                       unsigned short* __restrict__ hfb,
                       unsigned char* __restrict__ f8b,
                       unsigned char* __restrict__ sc8) {
    int t = threadIdx.x;
    const u16x8 Z = {0, 0, 0, 0, 0, 0, 0, 0};
    if (t < 64)        *(u16x8*)&fb[(size_t)N * D + t * 8] = Z;
    else if (t < 80)   *(u16x8*)&scb[(size_t)N * KP + (t - 64) * 8] = Z;
    else if (t < 144)  *(u16x8*)&hfb[(size_t)N * D + (t - 80) * 8] = Z;
    else if (t < 176)  *(u16x8*)&f8b[(size_t)N * D + (size_t)(t - 144) * 16] = Z;
    else if (t < 184)  *(u16x8*)&sc8[(size_t)N * KP + (size_t)(t - 176) * 16] = Z;
}

// f32 [R][C] -> bf16 [C][R] transpose-convert
__global__ __launch_bounds__(256) void k_transpose(const float* __restrict__ in,
                                                   unsigned short* __restrict__ out,
                                                   int R, int C) {
    __shared__ float tile[32][33];
    int bx = blockIdx.x * 32, by = blockIdx.y * 32;
    int tx = threadIdx.x & 31, ty = threadIdx.x >> 5;   // ty 0..7
    #pragma unroll
    for (int i = 0; i < 32; i += 8)
        if (by + ty + i < R && bx + tx < C)
            tile[ty + i][tx] = in[(size_t)(by + ty + i) * C + bx + tx];
    __syncthreads();
    #pragma unroll
    for (int i = 0; i < 32; i += 8)
        if (bx + ty + i < C && by + tx < R)
            out[(size_t)(bx + ty + i) * R + by + tx] = f2bf(tile[tx][ty + i]);
}

// ---------------------------------------------------------------------------
// Graph build: padded bins (no counting pass) + LDS-staged coalesced writes
// ---------------------------------------------------------------------------
__global__ void k_init(int* __restrict__ rcur, int* __restrict__ bcur) {
    int t = threadIdx.x;
    if (t < NR) rcur[t] = t * RSTRIDE;
    bcur[t] = t * BSTRIDE;
}

// pass A: partition raw edges by dst>>8 into pairs1 (padded bins)
__global__ __launch_bounds__(256) void k_splitA(const int* __restrict__ src,
                                                const int* __restrict__ dst,
                                                int* __restrict__ rcur, int2* __restrict__ out1) {
    __shared__ int2 stg[EPB];
    __shared__ int h[256], lstart[256], gbase[256];
    __shared__ int ws[4];
    int t = threadIdx.x;
    int e0 = blockIdx.x * EPB;
    int sv[8], dv[8], bin[8], rank[8];
    #pragma unroll
    for (int i = 0; i < 8; ++i) {
        int e = e0 + t + i * 256;
        sv[i] = src[e]; dv[i] = dst[e];
    }
    h[t] = 0;
    __syncthreads();
    #pragma unroll
    for (int i = 0; i < 8; ++i) {
        bin[i] = dv[i] >> 8;
        rank[i] = atomicAdd(&h[bin[i]], 1);
    }
    __syncthreads();
    {
        int v = h[t];
        int incl = block_incl_scan(v, ws);
        lstart[t] = incl - v;
        gbase[t] = v ? atomicAdd(&rcur[t], v) : 0;
    }
    __syncthreads();
    #pragma unroll
    for (int i = 0; i < 8; ++i)
        stg[lstart[bin[i]] + rank[i]] = int2{sv[i], dv[i]};
    __syncthreads();
    for (int i = t; i < EPB; i += 256) {
        int2 e = stg[i];
        int b = e.y >> 8;
        out1[gbase[b] + i - lstart[b]] = e;
    }
}

// pass B: partition pairs1 (already dst-range-ordered) by (gs,gd) bucket.
// Preserving pairs1's chunk locality gives each bucket dst-local runs ->
// V-side gathers in adj become L1/L2-hot (<=64KB window per run).
// 2 blocks per dst-range bin; fixed 9-iter unroll keeps arrays in registers.
__global__ __launch_bounds__(256) void k_splitB(const int2* __restrict__ pairs,
                                                const int* __restrict__ rcur,
                                                int* __restrict__ bcur, int2* __restrict__ out2) {
    __shared__ int2 stg[RSTRIDE / 2];
    __shared__ int h[256], lstart[256], gbase[256];
    __shared__ int ws[4];
    int t = threadIdx.x;
    int r = blockIdx.x >> 1, half = blockIdx.x & 1;
    int p0 = r * RSTRIDE, p1 = rcur[r], len = p1 - p0;
    int s0 = p0 + (len * half) / 2;
    int s1 = p0 + (len * (half + 1)) / 2;
    int cnt = s1 - s0;
    int sv[9], dv[9], bin[9], rank[9];
    h[t] = 0;
    __syncthreads();
    #pragma unroll
    for (int i = 0; i < 9; ++i) {
        int p = s0 + t + i * 256;
        if (p < s1) {
            int2 e = pairs[p];
            sv[i] = e.x; dv[i] = e.y;
            bin[i] = (e.x / NP) * B + e.y / NP;
            rank[i] = atomicAdd(&h[bin[i]], 1);
        }
    }
    __syncthreads();
    {
        int v = h[t];
        int incl = block_incl_scan(v, ws);
        lstart[t] = incl - v;
        gbase[t] = v ? atomicAdd(&bcur[t], v) : 0;
    }
    __syncthreads();
    #pragma unroll
    for (int i = 0; i < 9; ++i) {
        int p = s0 + t + i * 256;
        if (p < s1)
            stg[lstart[bin[i]] + rank[i]] = int2{sv[i], dv[i]};
    }
    __syncthreads();
    for (int i = t; i < cnt; i += 256) {
        int2 e = stg[i];
        int b = (e.x / NP) * B + e.y / NP;
        out2[gbase[b] + i - lstart[b]] = e;
    }
}

// per 256-node range: exact-dst counting sort -> rowstart + deg + csr
__global__ __launch_bounds__(256) void k_part2(const int2* __restrict__ pairs,
                                               const int* __restrict__ rcur,
                                               int* __restrict__ rowstart,
                                               int* __restrict__ degv,
                                               int* __restrict__ csr) {
    __shared__ int h[256];
    __shared__ int ws[4];
    int t = threadIdx.x;
    int r = blockIdx.x;
    int p0 = r * RSTRIDE, p1 = rcur[r];
    h[t] = 0;
    __syncthreads();
    for (int p = p0 + t; p < p1; p += 256)
        atomicAdd(&h[pairs[p].y & 255], 1);
    __syncthreads();
    int v = h[t];
    int incl = block_incl_scan(v, ws);
    int start = p0 + incl - v;
    __syncthreads();
    h[t] = start;
    rowstart[r * 256 + t] = start;
    degv[r * 256 + t] = v;
    __syncthreads();
    for (int p = p0 + t; p < p1; p += 256) {
        int2 e = pairs[p];
        int pos = atomicAdd(&h[e.y & 255], 1);
        csr[pos] = e.x;
    }
}

// ---------------------------------------------------------------------------
// xplus = feat + mean_neighbors(feat).  fp8 gathers, f32 accum, bf16 self.
// ---------------------------------------------------------------------------
__global__ __launch_bounds__(256) void k_agg(const unsigned short* __restrict__ fb,
                                             const unsigned char* __restrict__ f8,
                                             const int* __restrict__ rowstart,
                                             const int* __restrict__ degv,
                                             const int* __restrict__ csr,
                                             unsigned short* __restrict__ xb) {
    int w = threadIdx.x >> 6, lane = threadIdx.x & 63;
    int node = blockIdx.x * 4 + w;
    int r0 = rowstart[node], dg = degv[node], r1 = r0 + dg;
    u16x8 self = *(const u16x8*)&fb[(size_t)node * D + lane * 8];
    float a[8] = {};
    for (int base = r0; base < r1; base += 64) {
        int ii = base + lane;
        int idx = N;
        if (ii < r1) idx = csr[ii];
        int cnt = r1 - base; if (cnt > 64) cnt = 64;
        int batches = (cnt + 7) & ~7;
        for (int j = 0; j < batches; j += 8) {
            int s0 = __shfl(idx, j + 0), s1 = __shfl(idx, j + 1);
            int s2 = __shfl(idx, j + 2), s3 = __shfl(idx, j + 3);
            int s4 = __shfl(idx, j + 4), s5 = __shfl(idx, j + 5);
            int s6 = __shfl(idx, j + 6), s7 = __shfl(idx, j + 7);
            uint2 g0 = *(const uint2*)&f8[(size_t)s0 * D + lane * 8];
            uint2 g1 = *(const uint2*)&f8[(size_t)s1 * D + lane * 8];
            uint2 g2 = *(const uint2*)&f8[(size_t)s2 * D + lane * 8];
            uint2 g3 = *(const uint2*)&f8[(size_t)s3 * D + lane * 8];
            uint2 g4 = *(const uint2*)&f8[(size_t)s4 * D + lane * 8];
            uint2 g5 = *(const uint2*)&f8[(size_t)s5 * D + lane * 8];
            uint2 g6 = *(const uint2*)&f8[(size_t)s6 * D + lane * 8];
            uint2 g7 = *(const uint2*)&f8[(size_t)s7 * D + lane * 8];
            acc8_fp8(a, g0); acc8_fp8(a, g1); acc8_fp8(a, g2); acc8_fp8(a, g3);
            acc8_fp8(a, g4); acc8_fp8(a, g5); acc8_fp8(a, g6); acc8_fp8(a, g7);
        }
    }
    float inv = 1.0f / fmaxf((float)dg, 1.0f);
    u16x8 o;
    #pragma unroll
    for (int q = 0; q < 8; ++q) o[q] = f2bf(bf2f(self[q]) + a[q] * inv);
    *(u16x8*)&xb[(size_t)node * D + lane * 8] = o;
}

// ---------------------------------------------------------------------------
// hfeat = relu(xplus @ W_feat + b) -> bf16.  MFMA 128x128 tile, 2x2 waves.
// ---------------------------------------------------------------------------
__global__ __launch_bounds__(256) void k_gemm_feat(const unsigned short* __restrict__ Xb,
                                                   const unsigned short* __restrict__ Wt,
                                                   const float* __restrict__ bias,
                                                   unsigned short* __restrict__ Hf) {
    __shared__ unsigned short As[128 * 64];
    __shared__ unsigned short Bs[128 * 64];
    int t = threadIdx.x, wid = t >> 6, lane = t & 63;
    int wm = wid >> 1, wn = wid & 1;
    int row0 = blockIdx.x * 128, col0 = blockIdx.y * 128;
    int r8 = lane >> 3, ch = (lane & 7) ^ r8;
    f32x4 acc[4][4] = {};
    for (int k0 = 0; k0 < D; k0 += 64) {
        #pragma unroll
        for (int i = 0; i < 4; ++i) {
            int rr = wid * 32 + i * 8;
            glds16(Xb + (size_t)(row0 + rr + r8) * D + k0 + ch * 8, As + rr * 64);
            glds16(Wt + (size_t)(col0 + rr + r8) * D + k0 + ch * 8, Bs + rr * 64);
        }
        __syncthreads();
        #pragma unroll
        for (int ks = 0; ks < 2; ++ks) {
            bf16x8 af[4], bfr[4];
            #pragma unroll
            for (int f = 0; f < 4; ++f) {
                int ra = wm * 64 + f * 16 + (lane & 15);
                af[f] = *(const bf16x8*)&As[ra * 64 + (((ks * 4 + (lane >> 4)) ^ (ra & 7)) << 3)];
                int rb = wn * 64 + f * 16 + (lane & 15);
                bfr[f] = *(const bf16x8*)&Bs[rb * 64 + (((ks * 4 + (lane >> 4)) ^ (rb & 7)) << 3)];
            }
            #pragma unroll
            for (int m = 0; m < 4; ++m)
                #pragma unroll
                for (int n = 0; n < 4; ++n)
                    acc[m][n] = __builtin_amdgcn_mfma_f32_16x16x32_bf16(af[m], bfr[n], acc[m][n], 0, 0, 0);
        }
        __syncthreads();
    }
    float bv[4];
    #pragma unroll
    for (int n = 0; n < 4; ++n) bv[n] = bias[col0 + wn * 64 + n * 16 + (lane & 15)];
    #pragma unroll
    for (int m = 0; m < 4; ++m)
        #pragma unroll
        for (int r = 0; r < 4; ++r) {
            int row = row0 + wm * 64 + m * 16 + (lane >> 4) * 4 + r;
            #pragma unroll
            for (int n = 0; n < 4; ++n) {
                int col = col0 + wn * 64 + n * 16 + (lane & 15);
                float v = fmaxf(acc[m][n][r] + bv[n], 0.f);
                Hf[(size_t)row * D + col] = f2bf(v);
            }
        }
}

// ---------------------------------------------------------------------------
// sc = softmax(relu(xplus @ Wp_g + b_g)) over 128 in-graph cols.
// Writes bf16 (for h) AND fp8 e4m3 scaled x16 (for adj; descaled by 1/256).
// ---------------------------------------------------------------------------
__global__ __launch_bounds__(256) void k_gemm_pool(const unsigned short* __restrict__ Xb,
                                                   const unsigned short* __restrict__ Wpt,
                                                   const float* __restrict__ bp,
                                                   unsigned short* __restrict__ sc,
                                                   unsigned char* __restrict__ sc8) {
    __shared__ unsigned short As[128 * 64];
    __shared__ unsigned short Bs[128 * 64];
    int t = threadIdx.x, wid = t >> 6, lane = t & 63;
    int bm = blockIdx.x;      // 0..31
    int g  = blockIdx.y;      // 0..15
    int row0 = g * NP + bm * 128;
    int nrows = NP - bm * 128; if (nrows > 128) nrows = 128;
    int col0 = g * KP;
    int r8 = lane >> 3, ch = (lane & 7) ^ r8;
    f32x4 acc[2][8] = {};
    for (int k0 = 0; k0 < D; k0 += 64) {
        #pragma unroll
        for (int i = 0; i < 4; ++i) {
            int rr = wid * 32 + i * 8;
            glds16(Xb + (size_t)(row0 + rr + r8) * D + k0 + ch * 8, As + rr * 64);
            glds16(Wpt + (size_t)(col0 + rr + r8) * D + k0 + ch * 8, Bs + rr * 64);
        }
        __syncthreads();
        #pragma unroll
        for (int ks = 0; ks < 2; ++ks) {
            bf16x8 af[2], bfr[8];
            #pragma unroll
            for (int m = 0; m < 2; ++m) {
                int ra = wid * 32 + m * 16 + (lane & 15);
                af[m] = *(const bf16x8*)&As[ra * 64 + (((ks * 4 + (lane >> 4)) ^ (ra & 7)) << 3)];
            }
            #pragma unroll
            for (int n = 0; n < 8; ++n) {
                int rb = n * 16 + (lane & 15);
                bfr[n] = *(const bf16x8*)&Bs[rb * 64 + (((ks * 4 + (lane >> 4)) ^ (rb & 7)) << 3)];
            }
            #pragma unroll
            for (int m = 0; m < 2; ++m)
                #pragma unroll
                for (int n = 0; n < 8; ++n)
                    acc[m][n] = __builtin_amdgcn_mfma_f32_16x16x32_bf16(af[m], bfr[n], acc[m][n], 0, 0, 0);
        }
        __syncthreads();
    }
    float bv[8];
    #pragma unroll
    for (int n = 0; n < 8; ++n) bv[n] = bp[col0 + n * 16 + (lane & 15)];
    #pragma unroll
    for (int m = 0; m < 2; ++m)
        #pragma unroll
        for (int r = 0; r < 4; ++r) {
            float v[8];
            #pragma unroll
            for (int n = 0; n < 8; ++n) v[n] = fmaxf(acc[m][n][r] + bv[n], 0.f);
            float mx = v[0];
            #pragma unroll
            for (int n = 1; n < 8; ++n) mx = fmaxf(mx, v[n]);
            #pragma unroll
            for (int off = 1; off < 16; off <<= 1) mx = fmaxf(mx, __shfl_xor(mx, off));
            float ssum = 0.f;
            #pragma unroll
            for (int n = 0; n < 8; ++n) { v[n] = __expf(v[n] - mx); ssum += v[n]; }
            #pragma unroll
            for (int off = 1; off < 16; off <<= 1) ssum += __shfl_xor(ssum, off);
            float inv = 1.0f / ssum;
            int rowl = wid * 32 + m * 16 + (lane >> 4) * 4 + r;
            if (rowl < nrows) {
                #pragma unroll
                for (int n = 0; n < 8; ++n) {
                    float sv = v[n] * inv;
                    int col = n * 16 + (lane & 15);
                    sc[(size_t)(row0 + rowl) * KP + col] = f2bf(sv);
                    sc8[(size_t)(row0 + rowl) * KP + col] = f2fp8(sv * 16.0f);
                }
            }
        }
}

// ---------------------------------------------------------------------------
// Fused k_h + k_adj dispatch (k_ha).
//  h: bf16 operands, XOR-swizzled u16 stage.
//  adj: fp8 operands (sc8, scaled x16), byte LDS stage, fp8 MFMA, acc/256.
//  2-tile register pipeline in both.  adj g1 XCD-pinned; buckets dst-ordered.
// ---------------------------------------------------------------------------
constexpr int VBASE = 4128;    // u16 index of V section (h path, byte 8256)
constexpr int VB8   = 4128;    // byte index of V section (adj fp8 path)
constexpr int ADJ_SPLIT = 8;
constexpr int KZ_H = 16;

__device__ __forceinline__ void uv_write(unsigned short* arr, int c0, int es,
                                         const u16x8& l0, const u16x8& l1,
                                         const u16x8& l2, const u16x8& l3) {
    #pragma unroll
    for (int q = 0; q < 8; ++q) {
        int r0 = c0 + q, r1 = c0 + 8 + q, r2 = c0 + 16 + q, r3 = c0 + 24 + q;
        arr[r0 * 32 + (es ^ (((r0 >> 1) & 3) << 3))] = l0[q];
        arr[r1 * 32 + (es ^ (((r1 >> 1) & 3) << 3))] = l1[q];
        arr[r2 * 32 + (es ^ (((r2 >> 1) & 3) << 3))] = l2[q];
        arr[r3 * 32 + (es ^ (((r3 >> 1) & 3) << 3))] = l3[q];
    }
}

__device__ __forceinline__ void row_load(const unsigned short* row,
                                         u16x8& l0, u16x8& l1, u16x8& l2, u16x8& l3) {
    l0 = *(const u16x8*)(row);
    l1 = *(const u16x8*)(row + 8);
    l2 = *(const u16x8*)(row + 16);
    l3 = *(const u16x8*)(row + 24);
}

__device__ __forceinline__ bf16x8 uv_read(const unsigned short* UV, int base,
                                          int row, int chunk) {
    int c = chunk ^ ((row >> 1) & 3);
    return *(const bf16x8*)&UV[base + row * 32 + c * 8];
}

__device__ __forceinline__ void h_body(unsigned short* UV,
                                       const unsigned short* __restrict__ sc,
                                       const unsigned short* __restrict__ hf,
                                       float* __restrict__ outH,
                                       int g, int nt, int kz) {
    int t = threadIdx.x, wid = t >> 6, lane = t & 63;
    int n0 = nt * 128;
    int i0 = g * NP + kz * (NP / KZ_H), i1 = i0 + NP / KZ_H;   // 250 nodes
    int c0 = wid * 32;
    int es = lane & 31, op = lane >> 5;   // op0 = S(cluster), op1 = H(dim)
    unsigned short* arr = &UV[op * VBASE];
    f32x4 acc[2][8] = {};

    const unsigned short* baseptr = op ? (hf + n0 + c0) : (sc + c0);
    int rstride = op ? D : KP;
    auto mkrow = [&](int tbase) -> const unsigned short* {
        int nd = tbase + es;
        nd = nd < i1 ? nd : N;
        return baseptr + (size_t)nd * rstride;
    };

    u16x8 a0, a1, a2, a3, b0, b1, b2, b3;
    row_load(mkrow(i0), a0, a1, a2, a3);
    row_load(mkrow(i0 + 32), b0, b1, b2, b3);

    int ntile = (i1 - i0 + 31) >> 5;          // = 8 for 250 nodes
    for (int tt = 0; tt < ntile; tt += 2) {
        __syncthreads();
        uv_write(arr, c0, es, a0, a1, a2, a3);
        __syncthreads();
        row_load(mkrow(i0 + (tt + 2) * 32), a0, a1, a2, a3);
        {
            bf16x8 af[2], bfr[8];
            #pragma unroll
            for (int m = 0; m < 2; ++m)
                af[m] = uv_read(UV, 0, wid * 32 + m * 16 + (lane & 15), lane >> 4);
            #pragma unroll
            for (int n = 0; n < 8; ++n)
                bfr[n] = uv_read(UV, VBASE, n * 16 + (lane & 15), lane >> 4);
            #pragma unroll
            for (int m = 0; m < 2; ++m)
                #pragma unroll
                for (int n = 0; n < 8; ++n)
                    acc[m][n] = __builtin_amdgcn_mfma_f32_16x16x32_bf16(af[m], bfr[n], acc[m][n], 0, 0, 0);
        }
        __syncthreads();
        uv_write(arr, c0, es, b0, b1, b2, b3);
        __syncthreads();
        row_load(mkrow(i0 + (tt + 3) * 32), b0, b1, b2, b3);
        {
            bf16x8 af[2], bfr[8];
            #pragma unroll
            for (int m = 0; m < 2; ++m)
                af[m] = uv_read(UV, 0, wid * 32 + m * 16 + (lane & 15), lane >> 4);
            #pragma unroll
            for (int n = 0; n < 8; ++n)
                bfr[n] = uv_read(UV, VBASE, n * 16 + (lane & 15), lane >> 4);
            #pragma unroll
            for (int m = 0; m < 2; ++m)
                #pragma unroll
                for (int n = 0; n < 8; ++n)
                    acc[m][n] = __builtin_amdgcn_mfma_f32_16x16x32_bf16(af[m], bfr[n], acc[m][n], 0, 0, 0);
        }
    }
    #pragma unroll
    for (int m = 0; m < 2; ++m)
        #pragma unroll
        for (int r = 0; r < 4; ++r) {
            int row = g * KP + wid * 32 + m * 16 + (lane >> 4) * 4 + r;
            #pragma unroll
            for (int n = 0; n < 8; ++n) {
                int col = n0 + n * 16 + (lane & 15);
                atomicAdd(&outH[(size_t)row * D + col], acc[m][n][r]);
            }
        }
}

// fp8 staging helpers for adj
__device__ __forceinline__ void uv_write8(unsigned char* arr, int c0, int es,
                                          const uint4& lo, const uint4& hi) {
    const unsigned* wsrc = (const unsigned*)&lo;
    const unsigned* wsrc2 = (const unsigned*)&hi;
    int eb = es & 7, ec = es >> 3;
    #pragma unroll
    for (int qi = 0; qi < 16; ++qi) {
        {
            int row = c0 + qi;
            unsigned byte = (wsrc[qi >> 2] >> ((qi & 3) * 8)) & 255u;
            arr[row * 32 + (((ec ^ ((row >> 2) & 3)) << 3) | eb)] = (unsigned char)byte;
        }
        {
            int row = c0 + 16 + qi;
            unsigned byte = (wsrc2[qi >> 2] >> ((qi & 3) * 8)) & 255u;
            arr[row * 32 + (((ec ^ ((row >> 2) & 3)) << 3) | eb)] = (unsigned char)byte;
        }
    }
}

__device__ __forceinline__ long long uv_read8(const unsigned char* UV8, int base,
                                              int row, int chunk) {
    int c = chunk ^ ((row >> 2) & 3);
    return *(const long long*)&UV8[base + row * 32 + c * 8];
}

__device__ __forceinline__ void adj_body(unsigned char* UV8,
                                         const unsigned char* __restrict__ sc8,
                                         const int2* __restrict__ bpairs,
                                         const int* __restrict__ bcur,
                                         float* __restrict__ outA,
                                         int g1, int g2, int part) {
    int t = threadIdx.x, wid = t >> 6, lane = t & 63;
    int b = g1 * B + g2;
    int e0 = b * BSTRIDE, e1 = bcur[b], cnt = e1 - e0;
    int s0 = e0 + (int)((long long)cnt * part / ADJ_SPLIT);
    int s1 = e0 + (int)((long long)cnt * (part + 1) / ADJ_SPLIT);
    int c0 = wid * 32;
    int es = lane & 31, op = lane >> 5;   // op0 = U(src), op1 = V(dst)
    unsigned char* arr = &UV8[op * VB8];
    f32x4 acc[2][8] = {};

    auto mkrow = [&](int tbase) -> const unsigned char* {
        int idx = tbase + es;
        bool v = idx < s1;
        int2 e = bpairs[v ? idx : s0];
        int node = v ? (op ? e.y : e.x) : N;
        return sc8 + (size_t)node * KP + c0;
    };

    uint4 alo, ahi, blo, bhi;
    { const unsigned char* r = mkrow(s0);      alo = *(const uint4*)r; ahi = *(const uint4*)(r + 16); }
    { const unsigned char* r = mkrow(s0 + 32); blo = *(const uint4*)r; bhi = *(const uint4*)(r + 16); }

    int ntile = (s1 - s0 + 31) >> 5;
    for (int tt = 0; tt < ntile; tt += 2) {
        __syncthreads();
        uv_write8(arr, c0, es, alo, ahi);
        __syncthreads();
        { const unsigned char* r = mkrow(s0 + (tt + 2) * 32); alo = *(const uint4*)r; ahi = *(const uint4*)(r + 16); }
        {
            long long af[2], bfr[8];
            #pragma unroll
            for (int m = 0; m < 2; ++m)
                af[m] = uv_read8(UV8, 0, wid * 32 + m * 16 + (lane & 15), lane >> 4);
            #pragma unroll
            for (int n = 0; n < 8; ++n)
                bfr[n] = uv_read8(UV8, VB8, n * 16 + (lane & 15), lane >> 4);
            #pragma unroll
            for (int m = 0; m < 2; ++m)
                #pragma unroll
                for (int n = 0; n < 8; ++n)
                    acc[m][n] = __builtin_amdgcn_mfma_f32_16x16x32_fp8_fp8(af[m], bfr[n], acc[m][n], 0, 0, 0);
        }
        __syncthreads();
        uv_write8(arr, c0, es, blo, bhi);
        __syncthreads();
        { const unsigned char* r = mkrow(s0 + (tt + 3) * 32); blo = *(const uint4*)r; bhi = *(const uint4*)(r + 16); }
        {
            long long af[2], bfr[8];
            #pragma unroll
            for (int m = 0; m < 2; ++m)
                af[m] = uv_read8(UV8, 0, wid * 32 + m * 16 + (lane & 15), lane >> 4);
            #pragma unroll
            for (int n = 0; n < 8; ++n)
                bfr[n] = uv_read8(UV8, VB8, n * 16 + (lane & 15), lane >> 4);
            #pragma unroll
            for (int m = 0; m < 2; ++m)
                #pragma unroll
                for (int n = 0; n < 8; ++n)
                    acc[m][n] = __builtin_amdgcn_mfma_f32_16x16x32_fp8_fp8(af[m], bfr[n], acc[m][n], 0, 0, 0);
        }
    }
    const float DS = 1.0f / 256.0f;   // undo the x16 scale on both operands
    #pragma unroll
    for (int m = 0; m < 2; ++m)
        #pragma unroll
        for (int r = 0; r < 4; ++r) {
            int row = g1 * KP + wid * 32 + m * 16 + (lane >> 4) * 4 + r;
            #pragma unroll
            for (int n = 0; n < 8; ++n) {
                int col = g2 * KP + n * 16 + (lane & 15);
                atomicAdd(&outA[(size_t)row * KT + col], acc[m][n][r] * DS);
            }
        }
}

// grid = 3072 blocks = 12 slabs of 256; slabs with k%3==2 run h (4 slabs =
// 1024 h tiles), others adj (8 slabs = 2048 adj parts, ADJ_SPLIT=8).
// adj mapping (bijective): xcd = a&7, idx = a>>3; g1 = 2*xcd + (idx&1) so
// each XCD touches only 2 graphs' U rows (1MB fp8, L2-resident); g2/part
// free-run.  All remaps perf-only.
__global__ __launch_bounds__(256) void k_ha(const unsigned short* __restrict__ sc,
                                            const unsigned char* __restrict__ sc8,
                                            const unsigned short* __restrict__ hf,
                                            const int2* __restrict__ bpairs,
                                            const int* __restrict__ bcur,
                                            float* __restrict__ outH,
                                            float* __restrict__ outA) {
    __shared__ __align__(16) unsigned short UV[8224];
    int lin = blockIdx.x;
    int k = lin >> 8, rem = lin & 255;
    if (k % 3 == 2) {
        int hbase = (k / 3) * 256 + rem;          // [0,1024)
        int g = hbase & 15, nt = (hbase >> 4) & 3, kz = hbase >> 6;
        h_body(UV, sc, hf, outH, g, nt, kz);
    } else {
        int adjIdx = k - (k + 1) / 3;             // 0..7
        int base = adjIdx * 256 + rem;            // [0,2048)
        int xcd = base & 7, idx = base >> 3;
        int g1 = 2 * xcd + (idx & 1);
        int g2 = (idx >> 1) & 15;
        int part = (idx >> 5) & 7;
        adj_body((unsigned char*)UV, sc8, bpairs, bcur, outA, g1, g2, part);
    }
}

// ---------------------------------------------------------------------------
extern "C" void kernel_launch(void* const* d_in, const int* in_sizes, int n_in,
                              void* d_out, int out_size, void* d_ws, size_t ws_size,
                              hipStream_t stream) {
    const float* feat   = (const float*)d_in[0];
    const float* W_feat = (const float*)d_in[1];
    const float* b_feat = (const float*)d_in[2];
    const float* W_pool = (const float*)d_in[3];
    const float* b_pool = (const float*)d_in[4];
    const int*   src    = (const int*)d_in[5];
    const int*   dst    = (const int*)d_in[6];

    char* w = (char*)d_ws;
    unsigned short* fb  = (unsigned short*)w; w += (size_t)(N + 1) * D * 2;   // feat bf16 (+zero row)
    unsigned char*  f8b = (unsigned char*)w;  w += (size_t)(N + 1) * D;       // feat fp8 (+zero row)
    unsigned short* xb  = (unsigned short*)w; w += (size_t)N * D * 2;          // xplus bf16
    unsigned short* hfb = (unsigned short*)w; w += (size_t)(N + 1) * D * 2;   // hfeat bf16 (+zero row)
    unsigned short* scb = (unsigned short*)w; w += (size_t)(N + 1) * KP * 2;  // s bf16 (+zero row)
    unsigned char*  sc8 = (unsigned char*)w;  w += (size_t)(N + 1) * KP;      // s fp8 x16 (+zero row)
    unsigned short* Wt  = (unsigned short*)w; w += (size_t)D * D * 2;          // W_feat^T
    unsigned short* Wpt = (unsigned short*)w; w += (size_t)KT * D * 2;         // W_pool^T
    int2* pairs1  = (int2*)w; w += (size_t)NR * RSTRIDE * 8;    // padded dst-range bins
    int2* bpairs  = (int2*)w; w += (size_t)256 * BSTRIDE * 8;   // padded (gs,gd) buckets
    int*  csr     = (int*)w;  w += ((size_t)NR * RSTRIDE + 64) * 4;
    int*  rowstart= (int*)w;  w += (size_t)N * 4;
    int*  degv    = (int*)w;  w += (size_t)N * 4;
    int*  rcur    = (int*)w;  w += NR * 4;
    int*  bcur    = (int*)w;  w += 256 * 4;

    hipMemsetAsync(d_out, 0, (size_t)out_size * sizeof(float), stream);

    // conversions + pad rows
    k_cvt<<<(int)(((long long)N * D) / (8 * 256)), 256, 0, stream>>>(feat, fb, f8b, (long long)N * D);
    k_zrow<<<1, 256, 0, stream>>>(fb, scb, hfb, f8b, sc8);
    dim3 gt1(D / 32, D / 32);
    k_transpose<<<gt1, 256, 0, stream>>>(W_feat, Wt, D, D);
    dim3 gt2(KT / 32, D / 32);
    k_transpose<<<gt2, 256, 0, stream>>>(W_pool, Wpt, D, KT);

    // graph structure: pass A (dst-range bins), pass B (dst-ordered buckets)
    k_init<<<1, 256, 0, stream>>>(rcur, bcur);
    k_splitA<<<NPB, 256, 0, stream>>>(src, dst, rcur, pairs1);
    k_splitB<<<2 * NR, 256, 0, stream>>>(pairs1, rcur, bcur, bpairs);
    k_part2<<<NR, 256, 0, stream>>>(pairs1, rcur, rowstart, degv, csr);

    // aggregation + GEMMs
    k_agg<<<N / 4, 256, 0, stream>>>(fb, f8b, rowstart, degv, csr, xb);
    dim3 gf(N / 128, D / 128);
    k_gemm_feat<<<gf, 256, 0, stream>>>(xb, Wt, b_feat, hfb);
    dim3 gp(32, B);
    k_gemm_pool<<<gp, 256, 0, stream>>>(xb, Wpt, b_pool, scb, sc8);

    // fused h + adj (3072 blocks: 2048 adj parts + 1024 h tiles, mixed)
    k_ha<<<3072, 256, 0, stream>>>(scb, sc8, hfb, bpairs, bcur,
                                   (float*)d_out + (size_t)KT * KT, (float*)d_out);
}

// Round 14
// 413.422 us; speedup vs baseline: 1.0844x; 1.0844x over previous
//
#include <hip/hip_runtime.h>
#include <math.h>

// Problem constants (fixed by the reference)
constexpr int N  = 64000;
constexpr int E  = 1024000;
constexpr int D  = 512;
constexpr int KT = 2048;
constexpr int B  = 16;
constexpr int NP = 4000;   // nodes per graph
constexpr int KP = 128;    // clusters per graph
constexpr int NR = N / 256;        // 250 dst-ranges of 256 nodes
constexpr int EPB = 2048;          // edges per split block
constexpr int NPB = E / EPB;       // 500 split blocks
constexpr int RSTRIDE = 4608;      // padded bin stride (Poisson 4096 +8 sigma)
constexpr int BSTRIDE = 4608;      // padded bucket stride (Poisson 4000 +9.6 sigma)

typedef __attribute__((ext_vector_type(4))) float f32x4;
typedef __attribute__((ext_vector_type(2))) float f32x2;
typedef __attribute__((ext_vector_type(8))) short bf16x8;   // MFMA A/B frag (8 bf16)
typedef __attribute__((ext_vector_type(8))) unsigned short u16x8;

__device__ __forceinline__ unsigned short f2bf(float f) {
    unsigned u = __builtin_bit_cast(unsigned, f);
    return (unsigned short)((u + 0x7FFFu + ((u >> 16) & 1u)) >> 16);
}
__device__ __forceinline__ float bf2f(unsigned short h) {
    unsigned u = (unsigned)h << 16;
    return __builtin_bit_cast(float, u);
}

// ---- fp8 e4m3 (OCP) encode/decode: HW pk-cvt if available, bit-exact fallback ----
__device__ __forceinline__ unsigned char f2fp8_sw(float f) {
    unsigned u = __builtin_bit_cast(unsigned, f);
    unsigned s = u >> 31;
    float a = fabsf(f);
    if (a > 448.f) a = 448.f;
    unsigned code;
    if (a < 0.015625f) {
        code = (unsigned)rintf(a * 512.0f);
    } else {
        unsigned au = __builtin_bit_cast(unsigned, a);
        unsigned mant = au & 0x7FFFFFu;
        unsigned rnd = 0x7FFFFu + ((mant >> 20) & 1u);
        unsigned r2 = au + rnd;
        int e = (int)(r2 >> 23) - 127;
        unsigned m3 = (r2 >> 20) & 7u;
        if (e > 8) { e = 8; m3 = 7; }
        code = (unsigned)((e + 7) << 3) | m3;
    }
    return (unsigned char)(code | (s << 7));
}
__device__ __forceinline__ float fp82f_sw(unsigned b) {
    unsigned s = b >> 7, e = (b >> 3) & 15u, m = b & 7u;
    float vn = __builtin_bit_cast(float, ((e + 120u) << 23) | (m << 20));
    float vs = (float)(int)m * 0x1p-9f;
    float v = e ? vn : vs;
    return s ? -v : v;
}

__device__ __forceinline__ unsigned char f2fp8(float f) {
#if __has_builtin(__builtin_amdgcn_cvt_pk_fp8_f32)
    int w = __builtin_amdgcn_cvt_pk_fp8_f32(f, 0.f, 0, false);
    return (unsigned char)(w & 0xFF);
#else
    return f2fp8_sw(f);
#endif
}

__device__ __forceinline__ unsigned pack4_fp8(float f0, float f1, float f2, float f3) {
#if __has_builtin(__builtin_amdgcn_cvt_pk_fp8_f32)
    int w = __builtin_amdgcn_cvt_pk_fp8_f32(f0, f1, 0, false);
    w = __builtin_amdgcn_cvt_pk_fp8_f32(f2, f3, w, true);
    return (unsigned)w;
#else
    return (unsigned)f2fp8_sw(f0) | ((unsigned)f2fp8_sw(f1) << 8) |
           ((unsigned)f2fp8_sw(f2) << 16) | ((unsigned)f2fp8_sw(f3) << 24);
#endif
}

__device__ __forceinline__ void acc8_fp8(float* a, uint2 w) {
#if __has_builtin(__builtin_amdgcn_cvt_pk_f32_fp8)
    f32x2 p0 = __builtin_amdgcn_cvt_pk_f32_fp8((int)w.x, false);
    f32x2 p1 = __builtin_amdgcn_cvt_pk_f32_fp8((int)w.x, true);
    f32x2 p2 = __builtin_amdgcn_cvt_pk_f32_fp8((int)w.y, false);
    f32x2 p3 = __builtin_amdgcn_cvt_pk_f32_fp8((int)w.y, true);
    a[0] += p0.x; a[1] += p0.y; a[2] += p1.x; a[3] += p1.y;
    a[4] += p2.x; a[5] += p2.y; a[6] += p3.x; a[7] += p3.y;
#else
    #pragma unroll
    for (int q = 0; q < 4; ++q) a[q] += fp82f_sw((w.x >> (8 * q)) & 255u);
    #pragma unroll
    for (int q = 0; q < 4; ++q) a[4 + q] += fp82f_sw((w.y >> (8 * q)) & 255u);
#endif
}

// async global->LDS, 16B per lane; lds dest must be wave-uniform base
typedef const __attribute__((address_space(1))) unsigned int* gas_u32p;
typedef __attribute__((address_space(3))) unsigned int* las_u32p;
__device__ __forceinline__ void glds16(const unsigned short* g, unsigned short* l) {
    __builtin_amdgcn_global_load_lds((gas_u32p)(const void*)g, (las_u32p)(void*)l, 16, 0, 0);
}

// block-wide (256 thr) inclusive scan; ws is 4-int LDS scratch
__device__ __forceinline__ int block_incl_scan(int v, int* ws) {
    int t = threadIdx.x, lane = t & 63, w = t >> 6;
    int x = v;
    #pragma unroll
    for (int off = 1; off < 64; off <<= 1) {
        int y = __shfl_up(x, off);
        if (lane >= off) x += y;
    }
    if (lane == 63) ws[w] = x;
    __syncthreads();
    if (t < 4) {
        int s = ws[t];
        #pragma unroll
        for (int off = 1; off < 4; off <<= 1) {
            int y = __shfl_up(s, off);
            if (t >= off) s += y;
        }
        ws[t] = s;
    }
    __syncthreads();
    return x + (w > 0 ? ws[w - 1] : 0);
}

// ---------------------------------------------------------------------------
// f32 -> bf16 + fp8 dual convert (n multiple of 8)
// ---------------------------------------------------------------------------
__global__ __launch_bounds__(256) void k_cvt(const float* __restrict__ in,
                                             unsigned short* __restrict__ outb,
                                             unsigned char* __restrict__ out8,
                                             long long n) {
    long long i = ((long long)blockIdx.x * 256 + threadIdx.x) * 8;
    if (i >= n) return;
    f32x4 a = *(const f32x4*)&in[i];
    f32x4 b = *(const f32x4*)&in[i + 4];
    u16x8 o;
    o[0] = f2bf(a.x); o[1] = f2bf(a.y); o[2] = f2bf(a.z); o[3] = f2bf(a.w);
    o[4] = f2bf(b.x); o[5] = f2bf(b.y); o[6] = f2bf(b.z); o[7] = f2bf(b.w);
    *(u16x8*)&outb[i] = o;
    uint2 w;
    w.x = pack4_fp8(a.x, a.y, a.z, a.w);
    w.y = pack4_fp8(b.x, b.y, b.z, b.w);
    *(uint2*)&out8[i] = w;
}

// zero the pad rows (row index N) of fb, scb, hfb, f8b, sc8 each launch
__global__ void k_zrow(unsigned short* __restrict__ fb,
                       unsigned short* __restrict__ scb,
                       unsigned short* __restrict__ hfb,
                       unsigned char* __restrict__ f8b,
                       unsigned char* __restrict__ sc8) {
    int t = threadIdx.x;
    const u16x8 Z = {0, 0, 0, 0, 0, 0, 0, 0};
    if (t < 64)        *(u16x8*)&fb[(size_t)N * D + t * 8] = Z;
    else if (t < 80)   *(u16x8*)&scb[(size_t)N * KP + (t - 64) * 8] = Z;
    else if (t < 144)  *(u16x8*)&hfb[(size_t)N * D + (t - 80) * 8] = Z;
    else if (t < 176)  *(u16x8*)&f8b[(size_t)N * D + (size_t)(t - 144) * 16] = Z;
    else if (t < 184)  *(u16x8*)&sc8[(size_t)N * KP + (size_t)(t - 176) * 16] = Z;
}

// f32 [R][C] -> bf16 [C][R] transpose-convert
__global__ __launch_bounds__(256) void k_transpose(const float* __restrict__ in,
                                                   unsigned short* __restrict__ out,
                                                   int R, int C) {
    __shared__ float tile[32][33];
    int bx = blockIdx.x * 32, by = blockIdx.y * 32;
    int tx = threadIdx.x & 31, ty = threadIdx.x >> 5;   // ty 0..7
    #pragma unroll
    for (int i = 0; i < 32; i += 8)
        if (by + ty + i < R && bx + tx < C)
            tile[ty + i][tx] = in[(size_t)(by + ty + i) * C + bx + tx];
    __syncthreads();
    #pragma unroll
    for (int i = 0; i < 32; i += 8)
        if (bx + ty + i < C && by + tx < R)
            out[(size_t)(bx + ty + i) * R + by + tx] = f2bf(tile[tx][ty + i]);
}

// ---------------------------------------------------------------------------
// Graph build: padded bins (no counting pass) + LDS-staged coalesced writes
// ---------------------------------------------------------------------------
__global__ void k_init(int* __restrict__ rcur, int* __restrict__ bcur) {
    int t = threadIdx.x;
    if (t < NR) rcur[t] = t * RSTRIDE;
    bcur[t] = t * BSTRIDE;
}

// pass A: partition raw edges by dst>>8 into pairs1 (padded bins)
__global__ __launch_bounds__(256) void k_splitA(const int* __restrict__ src,
                                                const int* __restrict__ dst,
                                                int* __restrict__ rcur, int2* __restrict__ out1) {
    __shared__ int2 stg[EPB];
    __shared__ int h[256], lstart[256], gbase[256];
    __shared__ int ws[4];
    int t = threadIdx.x;
    int e0 = blockIdx.x * EPB;
    int sv[8], dv[8], bin[8], rank[8];
    #pragma unroll
    for (int i = 0; i < 8; ++i) {
        int e = e0 + t + i * 256;
        sv[i] = src[e]; dv[i] = dst[e];
    }
    h[t] = 0;
    __syncthreads();
    #pragma unroll
    for (int i = 0; i < 8; ++i) {
        bin[i] = dv[i] >> 8;
        rank[i] = atomicAdd(&h[bin[i]], 1);
    }
    __syncthreads();
    {
        int v = h[t];
        int incl = block_incl_scan(v, ws);
        lstart[t] = incl - v;
        gbase[t] = v ? atomicAdd(&rcur[t], v) : 0;
    }
    __syncthreads();
    #pragma unroll
    for (int i = 0; i < 8; ++i)
        stg[lstart[bin[i]] + rank[i]] = int2{sv[i], dv[i]};
    __syncthreads();
    for (int i = t; i < EPB; i += 256) {
        int2 e = stg[i];
        int b = e.y >> 8;
        out1[gbase[b] + i - lstart[b]] = e;
    }
}

// pass B: partition pairs1 (already dst-range-ordered) by (gs,gd) bucket.
// Preserving pairs1's chunk locality gives each bucket dst-local runs ->
// V-side gathers in adj become L1/L2-hot (<=64KB window per run).
__global__ __launch_bounds__(256) void k_splitB(const int2* __restrict__ pairs,
                                                const int* __restrict__ rcur,
                                                int* __restrict__ bcur, int2* __restrict__ out2) {
    __shared__ int2 stg[RSTRIDE / 2];
    __shared__ int h[256], lstart[256], gbase[256];
    __shared__ int ws[4];
    int t = threadIdx.x;
    int r = blockIdx.x >> 1, half = blockIdx.x & 1;
    int p0 = r * RSTRIDE, p1 = rcur[r], len = p1 - p0;
    int s0 = p0 + (len * half) / 2;
    int s1 = p0 + (len * (half + 1)) / 2;
    int cnt = s1 - s0;
    int sv[9], dv[9], bin[9], rank[9];
    h[t] = 0;
    __syncthreads();
    #pragma unroll
    for (int i = 0; i < 9; ++i) {
        int p = s0 + t + i * 256;
        if (p < s1) {
            int2 e = pairs[p];
            sv[i] = e.x; dv[i] = e.y;
            bin[i] = (e.x / NP) * B + e.y / NP;
            rank[i] = atomicAdd(&h[bin[i]], 1);
        }
    }
    __syncthreads();
    {
        int v = h[t];
        int incl = block_incl_scan(v, ws);
        lstart[t] = incl - v;
        gbase[t] = v ? atomicAdd(&bcur[t], v) : 0;
    }
    __syncthreads();
    #pragma unroll
    for (int i = 0; i < 9; ++i) {
        int p = s0 + t + i * 256;
        if (p < s1)
            stg[lstart[bin[i]] + rank[i]] = int2{sv[i], dv[i]};
    }
    __syncthreads();
    for (int i = t; i < cnt; i += 256) {
        int2 e = stg[i];
        int b = (e.x / NP) * B + e.y / NP;
        out2[gbase[b] + i - lstart[b]] = e;
    }
}

// per 256-node range: exact-dst counting sort -> rowstart + deg + csr
__global__ __launch_bounds__(256) void k_part2(const int2* __restrict__ pairs,
                                               const int* __restrict__ rcur,
                                               int* __restrict__ rowstart,
                                               int* __restrict__ degv,
                                               int* __restrict__ csr) {
    __shared__ int h[256];
    __shared__ int ws[4];
    int t = threadIdx.x;
    int r = blockIdx.x;
    int p0 = r * RSTRIDE, p1 = rcur[r];
    h[t] = 0;
    __syncthreads();
    for (int p = p0 + t; p < p1; p += 256)
        atomicAdd(&h[pairs[p].y & 255], 1);
    __syncthreads();
    int v = h[t];
    int incl = block_incl_scan(v, ws);
    int start = p0 + incl - v;
    __syncthreads();
    h[t] = start;
    rowstart[r * 256 + t] = start;
    degv[r * 256 + t] = v;
    __syncthreads();
    for (int p = p0 + t; p < p1; p += 256) {
        int2 e = pairs[p];
        int pos = atomicAdd(&h[e.y & 255], 1);
        csr[pos] = e.x;
    }
}

// ---------------------------------------------------------------------------
// xplus = feat + mean_neighbors(feat).  fp8 gathers, f32 accum, bf16 self.
// ---------------------------------------------------------------------------
__global__ __launch_bounds__(256) void k_agg(const unsigned short* __restrict__ fb,
                                             const unsigned char* __restrict__ f8,
                                             const int* __restrict__ rowstart,
                                             const int* __restrict__ degv,
                                             const int* __restrict__ csr,
                                             unsigned short* __restrict__ xb) {
    int w = threadIdx.x >> 6, lane = threadIdx.x & 63;
    int node = blockIdx.x * 4 + w;
    int r0 = rowstart[node], dg = degv[node], r1 = r0 + dg;
    u16x8 self = *(const u16x8*)&fb[(size_t)node * D + lane * 8];
    float a[8] = {};
    for (int base = r0; base < r1; base += 64) {
        int ii = base + lane;
        int idx = N;
        if (ii < r1) idx = csr[ii];
        int cnt = r1 - base; if (cnt > 64) cnt = 64;
        int batches = (cnt + 7) & ~7;
        for (int j = 0; j < batches; j += 8) {
            int s0 = __shfl(idx, j + 0), s1 = __shfl(idx, j + 1);
            int s2 = __shfl(idx, j + 2), s3 = __shfl(idx, j + 3);
            int s4 = __shfl(idx, j + 4), s5 = __shfl(idx, j + 5);
            int s6 = __shfl(idx, j + 6), s7 = __shfl(idx, j + 7);
            uint2 g0 = *(const uint2*)&f8[(size_t)s0 * D + lane * 8];
            uint2 g1 = *(const uint2*)&f8[(size_t)s1 * D + lane * 8];
            uint2 g2 = *(const uint2*)&f8[(size_t)s2 * D + lane * 8];
            uint2 g3 = *(const uint2*)&f8[(size_t)s3 * D + lane * 8];
            uint2 g4 = *(const uint2*)&f8[(size_t)s4 * D + lane * 8];
            uint2 g5 = *(const uint2*)&f8[(size_t)s5 * D + lane * 8];
            uint2 g6 = *(const uint2*)&f8[(size_t)s6 * D + lane * 8];
            uint2 g7 = *(const uint2*)&f8[(size_t)s7 * D + lane * 8];
            acc8_fp8(a, g0); acc8_fp8(a, g1); acc8_fp8(a, g2); acc8_fp8(a, g3);
            acc8_fp8(a, g4); acc8_fp8(a, g5); acc8_fp8(a, g6); acc8_fp8(a, g7);
        }
    }
    float inv = 1.0f / fmaxf((float)dg, 1.0f);
    u16x8 o;
    #pragma unroll
    for (int q = 0; q < 8; ++q) o[q] = f2bf(bf2f(self[q]) + a[q] * inv);
    *(u16x8*)&xb[(size_t)node * D + lane * 8] = o;
}

// ---------------------------------------------------------------------------
// hfeat = relu(xplus @ W_feat + b) -> bf16.  MFMA 128x128 tile, 2x2 waves.
// ---------------------------------------------------------------------------
__global__ __launch_bounds__(256) void k_gemm_feat(const unsigned short* __restrict__ Xb,
                                                   const unsigned short* __restrict__ Wt,
                                                   const float* __restrict__ bias,
                                                   unsigned short* __restrict__ Hf) {
    __shared__ unsigned short As[128 * 64];
    __shared__ unsigned short Bs[128 * 64];
    int t = threadIdx.x, wid = t >> 6, lane = t & 63;
    int wm = wid >> 1, wn = wid & 1;
    int row0 = blockIdx.x * 128, col0 = blockIdx.y * 128;
    int r8 = lane >> 3, ch = (lane & 7) ^ r8;
    f32x4 acc[4][4] = {};
    for (int k0 = 0; k0 < D; k0 += 64) {
        #pragma unroll
        for (int i = 0; i < 4; ++i) {
            int rr = wid * 32 + i * 8;
            glds16(Xb + (size_t)(row0 + rr + r8) * D + k0 + ch * 8, As + rr * 64);
            glds16(Wt + (size_t)(col0 + rr + r8) * D + k0 + ch * 8, Bs + rr * 64);
        }
        __syncthreads();
        #pragma unroll
        for (int ks = 0; ks < 2; ++ks) {
            bf16x8 af[4], bfr[4];
            #pragma unroll
            for (int f = 0; f < 4; ++f) {
                int ra = wm * 64 + f * 16 + (lane & 15);
                af[f] = *(const bf16x8*)&As[ra * 64 + (((ks * 4 + (lane >> 4)) ^ (ra & 7)) << 3)];
                int rb = wn * 64 + f * 16 + (lane & 15);
                bfr[f] = *(const bf16x8*)&Bs[rb * 64 + (((ks * 4 + (lane >> 4)) ^ (rb & 7)) << 3)];
            }
            #pragma unroll
            for (int m = 0; m < 4; ++m)
                #pragma unroll
                for (int n = 0; n < 4; ++n)
                    acc[m][n] = __builtin_amdgcn_mfma_f32_16x16x32_bf16(af[m], bfr[n], acc[m][n], 0, 0, 0);
        }
        __syncthreads();
    }
    float bv[4];
    #pragma unroll
    for (int n = 0; n < 4; ++n) bv[n] = bias[col0 + wn * 64 + n * 16 + (lane & 15)];
    #pragma unroll
    for (int m = 0; m < 4; ++m)
        #pragma unroll
        for (int r = 0; r < 4; ++r) {
            int row = row0 + wm * 64 + m * 16 + (lane >> 4) * 4 + r;
            #pragma unroll
            for (int n = 0; n < 4; ++n) {
                int col = col0 + wn * 64 + n * 16 + (lane & 15);
                float v = fmaxf(acc[m][n][r] + bv[n], 0.f);
                Hf[(size_t)row * D + col] = f2bf(v);
            }
        }
}

// ---------------------------------------------------------------------------
// sc = softmax(relu(xplus @ Wp_g + b_g)) over 128 in-graph cols.
// Writes bf16 (for h) AND fp8 e4m3 scaled x16 (for adj; descaled by 1/256).
// ---------------------------------------------------------------------------
__global__ __launch_bounds__(256) void k_gemm_pool(const unsigned short* __restrict__ Xb,
                                                   const unsigned short* __restrict__ Wpt,
                                                   const float* __restrict__ bp,
                                                   unsigned short* __restrict__ sc,
                                                   unsigned char* __restrict__ sc8) {
    __shared__ unsigned short As[128 * 64];
    __shared__ unsigned short Bs[128 * 64];
    int t = threadIdx.x, wid = t >> 6, lane = t & 63;
    int bm = blockIdx.x;      // 0..31
    int g  = blockIdx.y;      // 0..15
    int row0 = g * NP + bm * 128;
    int nrows = NP - bm * 128; if (nrows > 128) nrows = 128;
    int col0 = g * KP;
    int r8 = lane >> 3, ch = (lane & 7) ^ r8;
    f32x4 acc[2][8] = {};
    for (int k0 = 0; k0 < D; k0 += 64) {
        #pragma unroll
        for (int i = 0; i < 4; ++i) {
            int rr = wid * 32 + i * 8;
            glds16(Xb + (size_t)(row0 + rr + r8) * D + k0 + ch * 8, As + rr * 64);
            glds16(Wpt + (size_t)(col0 + rr + r8) * D + k0 + ch * 8, Bs + rr * 64);
        }
        __syncthreads();
        #pragma unroll
        for (int ks = 0; ks < 2; ++ks) {
            bf16x8 af[2], bfr[8];
            #pragma unroll
            for (int m = 0; m < 2; ++m) {
                int ra = wid * 32 + m * 16 + (lane & 15);
                af[m] = *(const bf16x8*)&As[ra * 64 + (((ks * 4 + (lane >> 4)) ^ (ra & 7)) << 3)];
            }
            #pragma unroll
            for (int n = 0; n < 8; ++n) {
                int rb = n * 16 + (lane & 15);
                bfr[n] = *(const bf16x8*)&Bs[rb * 64 + (((ks * 4 + (lane >> 4)) ^ (rb & 7)) << 3)];
            }
            #pragma unroll
            for (int m = 0; m < 2; ++m)
                #pragma unroll
                for (int n = 0; n < 8; ++n)
                    acc[m][n] = __builtin_amdgcn_mfma_f32_16x16x32_bf16(af[m], bfr[n], acc[m][n], 0, 0, 0);
        }
        __syncthreads();
    }
    float bv[8];
    #pragma unroll
    for (int n = 0; n < 8; ++n) bv[n] = bp[col0 + n * 16 + (lane & 15)];
    #pragma unroll
    for (int m = 0; m < 2; ++m)
        #pragma unroll
        for (int r = 0; r < 4; ++r) {
            float v[8];
            #pragma unroll
            for (int n = 0; n < 8; ++n) v[n] = fmaxf(acc[m][n][r] + bv[n], 0.f);
            float mx = v[0];
            #pragma unroll
            for (int n = 1; n < 8; ++n) mx = fmaxf(mx, v[n]);
            #pragma unroll
            for (int off = 1; off < 16; off <<= 1) mx = fmaxf(mx, __shfl_xor(mx, off));
            float ssum = 0.f;
            #pragma unroll
            for (int n = 0; n < 8; ++n) { v[n] = __expf(v[n] - mx); ssum += v[n]; }
            #pragma unroll
            for (int off = 1; off < 16; off <<= 1) ssum += __shfl_xor(ssum, off);
            float inv = 1.0f / ssum;
            int rowl = wid * 32 + m * 16 + (lane >> 4) * 4 + r;
            if (rowl < nrows) {
                #pragma unroll
                for (int n = 0; n < 8; ++n) {
                    float sv = v[n] * inv;
                    int col = n * 16 + (lane & 15);
                    sc[(size_t)(row0 + rowl) * KP + col] = f2bf(sv);
                    sc8[(size_t)(row0 + rowl) * KP + col] = f2fp8(sv * 16.0f);
                }
            }
        }
}

// ---------------------------------------------------------------------------
// Fused k_h + k_adj dispatch (k_ha).
//  h: bf16 operands, XOR-swizzled u16 stage.
//  adj: fp8 operands (sc8, scaled x16), byte LDS stage, fp8 MFMA, acc/256.
//  2-tile register pipeline in both.  adj g1 XCD-pinned; buckets dst-ordered.
// ---------------------------------------------------------------------------
constexpr int VBASE = 4128;    // u16 index of V section (h path, byte 8256)
constexpr int VB8   = 4128;    // byte index of V section (adj fp8 path)
constexpr int ADJ_SPLIT = 4;
constexpr int KZ_H = 16;

__device__ __forceinline__ void uv_write(unsigned short* arr, int c0, int es,
                                         const u16x8& l0, const u16x8& l1,
                                         const u16x8& l2, const u16x8& l3) {
    #pragma unroll
    for (int q = 0; q < 8; ++q) {
        int r0 = c0 + q, r1 = c0 + 8 + q, r2 = c0 + 16 + q, r3 = c0 + 24 + q;
        arr[r0 * 32 + (es ^ (((r0 >> 1) & 3) << 3))] = l0[q];
        arr[r1 * 32 + (es ^ (((r1 >> 1) & 3) << 3))] = l1[q];
        arr[r2 * 32 + (es ^ (((r2 >> 1) & 3) << 3))] = l2[q];
        arr[r3 * 32 + (es ^ (((r3 >> 1) & 3) << 3))] = l3[q];
    }
}

__device__ __forceinline__ void row_load(const unsigned short* row,
                                         u16x8& l0, u16x8& l1, u16x8& l2, u16x8& l3) {
    l0 = *(const u16x8*)(row);
    l1 = *(const u16x8*)(row + 8);
    l2 = *(const u16x8*)(row + 16);
    l3 = *(const u16x8*)(row + 24);
}

__device__ __forceinline__ bf16x8 uv_read(const unsigned short* UV, int base,
                                          int row, int chunk) {
    int c = chunk ^ ((row >> 1) & 3);
    return *(const bf16x8*)&UV[base + row * 32 + c * 8];
}

__device__ __forceinline__ void h_body(unsigned short* UV,
                                       const unsigned short* __restrict__ sc,
                                       const unsigned short* __restrict__ hf,
                                       float* __restrict__ outH,
                                       int g, int nt, int kz) {
    int t = threadIdx.x, wid = t >> 6, lane = t & 63;
    int n0 = nt * 128;
    int i0 = g * NP + kz * (NP / KZ_H), i1 = i0 + NP / KZ_H;   // 250 nodes
    int c0 = wid * 32;
    int es = lane & 31, op = lane >> 5;   // op0 = S(cluster), op1 = H(dim)
    unsigned short* arr = &UV[op * VBASE];
    f32x4 acc[2][8] = {};

    const unsigned short* baseptr = op ? (hf + n0 + c0) : (sc + c0);
    int rstride = op ? D : KP;
    auto mkrow = [&](int tbase) -> const unsigned short* {
        int nd = tbase + es;
        nd = nd < i1 ? nd : N;
        return baseptr + (size_t)nd * rstride;
    };

    u16x8 a0, a1, a2, a3, b0, b1, b2, b3;
    row_load(mkrow(i0), a0, a1, a2, a3);
    row_load(mkrow(i0 + 32), b0, b1, b2, b3);

    int ntile = (i1 - i0 + 31) >> 5;          // = 8 for 250 nodes
    for (int tt = 0; tt < ntile; tt += 2) {
        __syncthreads();
        uv_write(arr, c0, es, a0, a1, a2, a3);
        __syncthreads();
        row_load(mkrow(i0 + (tt + 2) * 32), a0, a1, a2, a3);
        {
            bf16x8 af[2], bfr[8];
            #pragma unroll
            for (int m = 0; m < 2; ++m)
                af[m] = uv_read(UV, 0, wid * 32 + m * 16 + (lane & 15), lane >> 4);
            #pragma unroll
            for (int n = 0; n < 8; ++n)
                bfr[n] = uv_read(UV, VBASE, n * 16 + (lane & 15), lane >> 4);
            #pragma unroll
            for (int m = 0; m < 2; ++m)
                #pragma unroll
                for (int n = 0; n < 8; ++n)
                    acc[m][n] = __builtin_amdgcn_mfma_f32_16x16x32_bf16(af[m], bfr[n], acc[m][n], 0, 0, 0);
        }
        __syncthreads();
        uv_write(arr, c0, es, b0, b1, b2, b3);
        __syncthreads();
        row_load(mkrow(i0 + (tt + 3) * 32), b0, b1, b2, b3);
        {
            bf16x8 af[2], bfr[8];
            #pragma unroll
            for (int m = 0; m < 2; ++m)
                af[m] = uv_read(UV, 0, wid * 32 + m * 16 + (lane & 15), lane >> 4);
            #pragma unroll
            for (int n = 0; n < 8; ++n)
                bfr[n] = uv_read(UV, VBASE, n * 16 + (lane & 15), lane >> 4);
            #pragma unroll
            for (int m = 0; m < 2; ++m)
                #pragma unroll
                for (int n = 0; n < 8; ++n)
                    acc[m][n] = __builtin_amdgcn_mfma_f32_16x16x32_bf16(af[m], bfr[n], acc[m][n], 0, 0, 0);
        }
    }
    #pragma unroll
    for (int m = 0; m < 2; ++m)
        #pragma unroll
        for (int r = 0; r < 4; ++r) {
            int row = g * KP + wid * 32 + m * 16 + (lane >> 4) * 4 + r;
            #pragma unroll
            for (int n = 0; n < 8; ++n) {
                int col = n0 + n * 16 + (lane & 15);
                atomicAdd(&outH[(size_t)row * D + col], acc[m][n][r]);
            }
        }
}

// fp8 staging helpers for adj
__device__ __forceinline__ void uv_write8(unsigned char* arr, int c0, int es,
                                          const uint4& lo, const uint4& hi) {
    const unsigned* wsrc = (const unsigned*)&lo;
    const unsigned* wsrc2 = (const unsigned*)&hi;
    int eb = es & 7, ec = es >> 3;
    #pragma unroll
    for (int qi = 0; qi < 16; ++qi) {
        {
            int row = c0 + qi;
            unsigned byte = (wsrc[qi >> 2] >> ((qi & 3) * 8)) & 255u;
            arr[row * 32 + (((ec ^ ((row >> 2) & 3)) << 3) | eb)] = (unsigned char)byte;
        }
        {
            int row = c0 + 16 + qi;
            unsigned byte = (wsrc2[qi >> 2] >> ((qi & 3) * 8)) & 255u;
            arr[row * 32 + (((ec ^ ((row >> 2) & 3)) << 3) | eb)] = (unsigned char)byte;
        }
    }
}

__device__ __forceinline__ long long uv_read8(const unsigned char* UV8, int base,
                                              int row, int chunk) {
    int c = chunk ^ ((row >> 2) & 3);
    return *(const long long*)&UV8[base + row * 32 + c * 8];
}

__device__ __forceinline__ void adj_body(unsigned char* UV8,
                                         const unsigned char* __restrict__ sc8,
                                         const int2* __restrict__ bpairs,
                                         const int* __restrict__ bcur,
                                         float* __restrict__ outA,
                                         int g1, int g2, int part) {
    int t = threadIdx.x, wid = t >> 6, lane = t & 63;
    int b = g1 * B + g2;
    int e0 = b * BSTRIDE, e1 = bcur[b], cnt = e1 - e0;
    int s0 = e0 + (int)((long long)cnt * part / ADJ_SPLIT);
    int s1 = e0 + (int)((long long)cnt * (part + 1) / ADJ_SPLIT);
    int c0 = wid * 32;
    int es = lane & 31, op = lane >> 5;   // op0 = U(src), op1 = V(dst)
    unsigned char* arr = &UV8[op * VB8];
    f32x4 acc[2][8] = {};

    auto mkrow = [&](int tbase) -> const unsigned char* {
        int idx = tbase + es;
        bool v = idx < s1;
        int2 e = bpairs[v ? idx : s0];
        int node = v ? (op ? e.y : e.x) : N;
        return sc8 + (size_t)node * KP + c0;
    };

    uint4 alo, ahi, blo, bhi;
    { const unsigned char* r = mkrow(s0);      alo = *(const uint4*)r; ahi = *(const uint4*)(r + 16); }
    { const unsigned char* r = mkrow(s0 + 32); blo = *(const uint4*)r; bhi = *(const uint4*)(r + 16); }

    int ntile = (s1 - s0 + 31) >> 5;
    for (int tt = 0; tt < ntile; tt += 2) {
        __syncthreads();
        uv_write8(arr, c0, es, alo, ahi);
        __syncthreads();
        { const unsigned char* r = mkrow(s0 + (tt + 2) * 32); alo = *(const uint4*)r; ahi = *(const uint4*)(r + 16); }
        {
            long long af[2], bfr[8];
            #pragma unroll
            for (int m = 0; m < 2; ++m)
                af[m] = uv_read8(UV8, 0, wid * 32 + m * 16 + (lane & 15), lane >> 4);
            #pragma unroll
            for (int n = 0; n < 8; ++n)
                bfr[n] = uv_read8(UV8, VB8, n * 16 + (lane & 15), lane >> 4);
            #pragma unroll
            for (int m = 0; m < 2; ++m)
                #pragma unroll
                for (int n = 0; n < 8; ++n)
                    acc[m][n] = __builtin_amdgcn_mfma_f32_16x16x32_fp8_fp8(af[m], bfr[n], acc[m][n], 0, 0, 0);
        }
        __syncthreads();
        uv_write8(arr, c0, es, blo, bhi);
        __syncthreads();
        { const unsigned char* r = mkrow(s0 + (tt + 3) * 32); blo = *(const uint4*)r; bhi = *(const uint4*)(r + 16); }
        {
            long long af[2], bfr[8];
            #pragma unroll
            for (int m = 0; m < 2; ++m)
                af[m] = uv_read8(UV8, 0, wid * 32 + m * 16 + (lane & 15), lane >> 4);
            #pragma unroll
            for (int n = 0; n < 8; ++n)
                bfr[n] = uv_read8(UV8, VB8, n * 16 + (lane & 15), lane >> 4);
            #pragma unroll
            for (int m = 0; m < 2; ++m)
                #pragma unroll
                for (int n = 0; n < 8; ++n)
                    acc[m][n] = __builtin_amdgcn_mfma_f32_16x16x32_fp8_fp8(af[m], bfr[n], acc[m][n], 0, 0, 0);
        }
    }
    const float DS = 1.0f / 256.0f;   // undo the x16 scale on both operands
    #pragma unroll
    for (int m = 0; m < 2; ++m)
        #pragma unroll
        for (int r = 0; r < 4; ++r) {
            int row = g1 * KP + wid * 32 + m * 16 + (lane >> 4) * 4 + r;
            #pragma unroll
            for (int n = 0; n < 8; ++n) {
                int col = g2 * KP + n * 16 + (lane & 15);
                atomicAdd(&outA[(size_t)row * KT + col], acc[m][n][r] * DS);
            }
        }
}

// grid = 2048 blocks. role = bit8(lin): alternating 256-block slabs so under
// round-robin XCD dispatch each CU's resident blocks mix latency-bound adj
// with compute-bound h.  adj mapping (bijective): xcd = a&7, idx = a>>3,
// g1 = 2*xcd + (idx&1)  -> each XCD touches only 2 graphs' U rows (1MB fp8,
// L2-resident).  g2/part free-run so V streams.  Perf-only remap.
__global__ __launch_bounds__(256) void k_ha(const unsigned short* __restrict__ sc,
                                            const unsigned char* __restrict__ sc8,
                                            const unsigned short* __restrict__ hf,
                                            const int2* __restrict__ bpairs,
                                            const int* __restrict__ bcur,
                                            float* __restrict__ outH,
                                            float* __restrict__ outA) {
    __shared__ __align__(16) unsigned short UV[8224];
    int lin = blockIdx.x;
    int role = (lin >> 8) & 1;
    int base = (lin >> 9) * 256 + (lin & 255);   // [0,1024) per role
    if (role == 0) {
        int xcd = base & 7, idx = base >> 3;
        int g1 = 2 * xcd + (idx & 1);
        int g2 = (idx >> 1) & 15;
        int part = (idx >> 5) & 3;
        adj_body((unsigned char*)UV, sc8, bpairs, bcur, outA, g1, g2, part);
    } else {
        int g = base & 15, nt = (base >> 4) & 3, kz = base >> 6;
        h_body(UV, sc, hf, outH, g, nt, kz);
    }
}

// ---------------------------------------------------------------------------
extern "C" void kernel_launch(void* const* d_in, const int* in_sizes, int n_in,
                              void* d_out, int out_size, void* d_ws, size_t ws_size,
                              hipStream_t stream) {
    const float* feat   = (const float*)d_in[0];
    const float* W_feat = (const float*)d_in[1];
    const float* b_feat = (const float*)d_in[2];
    const float* W_pool = (const float*)d_in[3];
    const float* b_pool = (const float*)d_in[4];
    const int*   src    = (const int*)d_in[5];
    const int*   dst    = (const int*)d_in[6];

    char* w = (char*)d_ws;
    unsigned short* fb  = (unsigned short*)w; w += (size_t)(N + 1) * D * 2;   // feat bf16 (+zero row)
    unsigned char*  f8b = (unsigned char*)w;  w += (size_t)(N + 1) * D;       // feat fp8 (+zero row)
    unsigned short* xb  = (unsigned short*)w; w += (size_t)N * D * 2;          // xplus bf16
    unsigned short* hfb = (unsigned short*)w; w += (size_t)(N + 1) * D * 2;   // hfeat bf16 (+zero row)
    unsigned short* scb = (unsigned short*)w; w += (size_t)(N + 1) * KP * 2;  // s bf16 (+zero row)
    unsigned char*  sc8 = (unsigned char*)w;  w += (size_t)(N + 1) * KP;      // s fp8 x16 (+zero row)
    unsigned short* Wt  = (unsigned short*)w; w += (size_t)D * D * 2;          // W_feat^T
    unsigned short* Wpt = (unsigned short*)w; w += (size_t)KT * D * 2;         // W_pool^T
    int2* pairs1  = (int2*)w; w += (size_t)NR * RSTRIDE * 8;    // padded dst-range bins
    int2* bpairs  = (int2*)w; w += (size_t)256 * BSTRIDE * 8;   // padded (gs,gd) buckets
    int*  csr     = (int*)w;  w += ((size_t)NR * RSTRIDE + 64) * 4;
    int*  rowstart= (int*)w;  w += (size_t)N * 4;
    int*  degv    = (int*)w;  w += (size_t)N * 4;
    int*  rcur    = (int*)w;  w += NR * 4;
    int*  bcur    = (int*)w;  w += 256 * 4;

    hipMemsetAsync(d_out, 0, (size_t)out_size * sizeof(float), stream);

    // conversions + pad rows
    k_cvt<<<(int)(((long long)N * D) / (8 * 256)), 256, 0, stream>>>(feat, fb, f8b, (long long)N * D);
    k_zrow<<<1, 256, 0, stream>>>(fb, scb, hfb, f8b, sc8);
    dim3 gt1(D / 32, D / 32);
    k_transpose<<<gt1, 256, 0, stream>>>(W_feat, Wt, D, D);
    dim3 gt2(KT / 32, D / 32);
    k_transpose<<<gt2, 256, 0, stream>>>(W_pool, Wpt, D, KT);

    // graph structure: pass A (dst-range bins), pass B (dst-ordered buckets)
    k_init<<<1, 256, 0, stream>>>(rcur, bcur);
    k_splitA<<<NPB, 256, 0, stream>>>(src, dst, rcur, pairs1);
    k_splitB<<<2 * NR, 256, 0, stream>>>(pairs1, rcur, bcur, bpairs);
    k_part2<<<NR, 256, 0, stream>>>(pairs1, rcur, rowstart, degv, csr);

    // aggregation + GEMMs
    k_agg<<<N / 4, 256, 0, stream>>>(fb, f8b, rowstart, degv, csr, xb);
    dim3 gf(N / 128, D / 128);
    k_gemm_feat<<<gf, 256, 0, stream>>>(xb, Wt, b_feat, hfb);
    dim3 gp(32, B);
    k_gemm_pool<<<gp, 256, 0, stream>>>(xb, Wpt, b_pool, scb, sc8);

    // fused h + adj (2048 blocks: 1024 adj parts + 1024 h tiles, interleaved)
    k_ha<<<2048, 256, 0, stream>>>(scb, sc8, hfb, bpairs, bcur,
                                   (float*)d_out + (size_t)KT * KT, (float*)d_out);
}

// Round 15
// 387.172 us; speedup vs baseline: 1.1579x; 1.0678x over previous
//
#include <hip/hip_runtime.h>
#include <math.h>

// Problem constants (fixed by the reference)
constexpr int N  = 64000;
constexpr int E  = 1024000;
constexpr int D  = 512;
constexpr int KT = 2048;
constexpr int B  = 16;
constexpr int NP = 4000;   // nodes per graph
constexpr int KP = 128;    // clusters per graph
constexpr int NR = N / 256;        // 250 dst-ranges of 256 nodes
constexpr int EPB = 2048;          // edges per split block
constexpr int NPB = E / EPB;       // 500 split blocks
constexpr int RSTRIDE = 4608;      // padded bin stride (Poisson 4096 +8 sigma)
constexpr int BSTRIDE = 4608;      // padded bucket stride (Poisson 4000 +9.6 sigma)

typedef __attribute__((ext_vector_type(4))) float f32x4;
typedef __attribute__((ext_vector_type(2))) float f32x2;
typedef __attribute__((ext_vector_type(8))) short bf16x8;   // MFMA A/B frag (8 bf16)
typedef __attribute__((ext_vector_type(8))) unsigned short u16x8;

__device__ __forceinline__ unsigned short f2bf(float f) {
    unsigned u = __builtin_bit_cast(unsigned, f);
    return (unsigned short)((u + 0x7FFFu + ((u >> 16) & 1u)) >> 16);
}
__device__ __forceinline__ float bf2f(unsigned short h) {
    unsigned u = (unsigned)h << 16;
    return __builtin_bit_cast(float, u);
}

// ---- fp8 e4m3 (OCP) encode/decode: HW pk-cvt if available, bit-exact fallback ----
__device__ __forceinline__ unsigned char f2fp8_sw(float f) {
    unsigned u = __builtin_bit_cast(unsigned, f);
    unsigned s = u >> 31;
    float a = fabsf(f);
    if (a > 448.f) a = 448.f;
    unsigned code;
    if (a < 0.015625f) {
        code = (unsigned)rintf(a * 512.0f);
    } else {
        unsigned au = __builtin_bit_cast(unsigned, a);
        unsigned mant = au & 0x7FFFFFu;
        unsigned rnd = 0x7FFFFu + ((mant >> 20) & 1u);
        unsigned r2 = au + rnd;
        int e = (int)(r2 >> 23) - 127;
        unsigned m3 = (r2 >> 20) & 7u;
        if (e > 8) { e = 8; m3 = 7; }
        code = (unsigned)((e + 7) << 3) | m3;
    }
    return (unsigned char)(code | (s << 7));
}
__device__ __forceinline__ float fp82f_sw(unsigned b) {
    unsigned s = b >> 7, e = (b >> 3) & 15u, m = b & 7u;
    float vn = __builtin_bit_cast(float, ((e + 120u) << 23) | (m << 20));
    float vs = (float)(int)m * 0x1p-9f;
    float v = e ? vn : vs;
    return s ? -v : v;
}

__device__ __forceinline__ unsigned char f2fp8(float f) {
#if __has_builtin(__builtin_amdgcn_cvt_pk_fp8_f32)
    int w = __builtin_amdgcn_cvt_pk_fp8_f32(f, 0.f, 0, false);
    return (unsigned char)(w & 0xFF);
#else
    return f2fp8_sw(f);
#endif
}

__device__ __forceinline__ unsigned pack4_fp8(float f0, float f1, float f2, float f3) {
#if __has_builtin(__builtin_amdgcn_cvt_pk_fp8_f32)
    int w = __builtin_amdgcn_cvt_pk_fp8_f32(f0, f1, 0, false);
    w = __builtin_amdgcn_cvt_pk_fp8_f32(f2, f3, w, true);
    return (unsigned)w;
#else
    return (unsigned)f2fp8_sw(f0) | ((unsigned)f2fp8_sw(f1) << 8) |
           ((unsigned)f2fp8_sw(f2) << 16) | ((unsigned)f2fp8_sw(f3) << 24);
#endif
}

__device__ __forceinline__ void acc8_fp8(float* a, uint2 w) {
#if __has_builtin(__builtin_amdgcn_cvt_pk_f32_fp8)
    f32x2 p0 = __builtin_amdgcn_cvt_pk_f32_fp8((int)w.x, false);
    f32x2 p1 = __builtin_amdgcn_cvt_pk_f32_fp8((int)w.x, true);
    f32x2 p2 = __builtin_amdgcn_cvt_pk_f32_fp8((int)w.y, false);
    f32x2 p3 = __builtin_amdgcn_cvt_pk_f32_fp8((int)w.y, true);
    a[0] += p0.x; a[1] += p0.y; a[2] += p1.x; a[3] += p1.y;
    a[4] += p2.x; a[5] += p2.y; a[6] += p3.x; a[7] += p3.y;
#else
    #pragma unroll
    for (int q = 0; q < 4; ++q) a[q] += fp82f_sw((w.x >> (8 * q)) & 255u);
    #pragma unroll
    for (int q = 0; q < 4; ++q) a[4 + q] += fp82f_sw((w.y >> (8 * q)) & 255u);
#endif
}

// async global->LDS, 16B per lane; lds dest must be wave-uniform base
typedef const __attribute__((address_space(1))) unsigned int* gas_u32p;
typedef __attribute__((address_space(3))) unsigned int* las_u32p;
__device__ __forceinline__ void glds16(const unsigned short* g, unsigned short* l) {
    __builtin_amdgcn_global_load_lds((gas_u32p)(const void*)g, (las_u32p)(void*)l, 16, 0, 0);
}

// block-wide (256 thr) inclusive scan; ws is 4-int LDS scratch
__device__ __forceinline__ int block_incl_scan(int v, int* ws) {
    int t = threadIdx.x, lane = t & 63, w = t >> 6;
    int x = v;
    #pragma unroll
    for (int off = 1; off < 64; off <<= 1) {
        int y = __shfl_up(x, off);
        if (lane >= off) x += y;
    }
    if (lane == 63) ws[w] = x;
    __syncthreads();
    if (t < 4) {
        int s = ws[t];
        #pragma unroll
        for (int off = 1; off < 4; off <<= 1) {
            int y = __shfl_up(s, off);
            if (t >= off) s += y;
        }
        ws[t] = s;
    }
    __syncthreads();
    return x + (w > 0 ? ws[w - 1] : 0);
}

// ---------------------------------------------------------------------------
// f32 -> bf16 + fp8 dual convert (n multiple of 8)
// ---------------------------------------------------------------------------
__global__ __launch_bounds__(256) void k_cvt(const float* __restrict__ in,
                                             unsigned short* __restrict__ outb,
                                             unsigned char* __restrict__ out8,
                                             long long n) {
    long long i = ((long long)blockIdx.x * 256 + threadIdx.x) * 8;
    if (i >= n) return;
    f32x4 a = *(const f32x4*)&in[i];
    f32x4 b = *(const f32x4*)&in[i + 4];
    u16x8 o;
    o[0] = f2bf(a.x); o[1] = f2bf(a.y); o[2] = f2bf(a.z); o[3] = f2bf(a.w);
    o[4] = f2bf(b.x); o[5] = f2bf(b.y); o[6] = f2bf(b.z); o[7] = f2bf(b.w);
    *(u16x8*)&outb[i] = o;
    uint2 w;
    w.x = pack4_fp8(a.x, a.y, a.z, a.w);
    w.y = pack4_fp8(b.x, b.y, b.z, b.w);
    *(uint2*)&out8[i] = w;
}

// zero the pad rows (row index N) of fb, scb, hfb, f8b, sc8 each launch
__global__ void k_zrow(unsigned short* __restrict__ fb,
                       unsigned short* __restrict__ scb,
                       unsigned short* __restrict__ hfb,
                       unsigned char* __restrict__ f8b,
                       unsigned char* __restrict__ sc8) {
    int t = threadIdx.x;
    const u16x8 Z = {0, 0, 0, 0, 0, 0, 0, 0};
    if (t < 64)        *(u16x8*)&fb[(size_t)N * D + t * 8] = Z;
    else if (t < 80)   *(u16x8*)&scb[(size_t)N * KP + (t - 64) * 8] = Z;
    else if (t < 144)  *(u16x8*)&hfb[(size_t)N * D + (t - 80) * 8] = Z;
    else if (t < 176)  *(u16x8*)&f8b[(size_t)N * D + (size_t)(t - 144) * 16] = Z;
    else if (t < 184)  *(u16x8*)&sc8[(size_t)N * KP + (size_t)(t - 176) * 16] = Z;
}

// f32 [R][C] -> bf16 [C][R] transpose-convert
__global__ __launch_bounds__(256) void k_transpose(const float* __restrict__ in,
                                                   unsigned short* __restrict__ out,
                                                   int R, int C) {
    __shared__ float tile[32][33];
    int bx = blockIdx.x * 32, by = blockIdx.y * 32;
    int tx = threadIdx.x & 31, ty = threadIdx.x >> 5;   // ty 0..7
    #pragma unroll
    for (int i = 0; i < 32; i += 8)
        if (by + ty + i < R && bx + tx < C)
            tile[ty + i][tx] = in[(size_t)(by + ty + i) * C + bx + tx];
    __syncthreads();
    #pragma unroll
    for (int i = 0; i < 32; i += 8)
        if (bx + ty + i < C && by + tx < R)
            out[(size_t)(bx + ty + i) * R + by + tx] = f2bf(tile[tx][ty + i]);
}

// ---------------------------------------------------------------------------
// Graph build: padded bins (no counting pass) + LDS-staged coalesced writes
// ---------------------------------------------------------------------------
__global__ void k_init(int* __restrict__ rcur, int* __restrict__ bcur) {
    int t = threadIdx.x;
    if (t < NR) rcur[t] = t * RSTRIDE;
    bcur[t] = t * BSTRIDE;
}

// one pass: partition by dst>>8 into pairs1 AND by (gs,gd) into bpairs
__global__ __launch_bounds__(256) void k_split(const int* __restrict__ src,
                                               const int* __restrict__ dst,
                                               int* __restrict__ rcur, int2* __restrict__ out1,
                                               int* __restrict__ bcur, int2* __restrict__ out2) {
    __shared__ int2 stg[EPB];
    __shared__ int h[256], lstart[256], gbase[256];
    __shared__ int ws[4];
    int t = threadIdx.x;
    int e0 = blockIdx.x * EPB;
    int sv[8], dv[8], bin[8], rank[8];
    #pragma unroll
    for (int i = 0; i < 8; ++i) {
        int e = e0 + t + i * 256;
        sv[i] = src[e]; dv[i] = dst[e];
    }
    // ---- pass A: bin by dst>>8 ----
    h[t] = 0;
    __syncthreads();
    #pragma unroll
    for (int i = 0; i < 8; ++i) {
        bin[i] = dv[i] >> 8;
        rank[i] = atomicAdd(&h[bin[i]], 1);
    }
    __syncthreads();
    {
        int v = h[t];
        int incl = block_incl_scan(v, ws);
        lstart[t] = incl - v;
        gbase[t] = v ? atomicAdd(&rcur[t], v) : 0;
    }
    __syncthreads();
    #pragma unroll
    for (int i = 0; i < 8; ++i)
        stg[lstart[bin[i]] + rank[i]] = int2{sv[i], dv[i]};
    __syncthreads();
    for (int i = t; i < EPB; i += 256) {
        int2 e = stg[i];
        int b = e.y >> 8;
        out1[gbase[b] + i - lstart[b]] = e;
    }
    __syncthreads();
    // ---- pass B: bin by (gs,gd) bucket ----
    h[t] = 0;
    __syncthreads();
    #pragma unroll
    for (int i = 0; i < 8; ++i) {
        bin[i] = (sv[i] / NP) * B + dv[i] / NP;
        rank[i] = atomicAdd(&h[bin[i]], 1);
    }
    __syncthreads();
    {
        int v = h[t];
        int incl = block_incl_scan(v, ws);
        lstart[t] = incl - v;
        gbase[t] = v ? atomicAdd(&bcur[t], v) : 0;
    }
    __syncthreads();
    #pragma unroll
    for (int i = 0; i < 8; ++i)
        stg[lstart[bin[i]] + rank[i]] = int2{sv[i], dv[i]};
    __syncthreads();
    for (int i = t; i < EPB; i += 256) {
        int2 e = stg[i];
        int b = (e.x / NP) * B + e.y / NP;
        out2[gbase[b] + i - lstart[b]] = e;
    }
}

// per 256-node range: exact-dst counting sort -> rowstart + deg + csr
__global__ __launch_bounds__(256) void k_part2(const int2* __restrict__ pairs,
                                               const int* __restrict__ rcur,
                                               int* __restrict__ rowstart,
                                               int* __restrict__ degv,
                                               int* __restrict__ csr) {
    __shared__ int h[256];
    __shared__ int ws[4];
    int t = threadIdx.x;
    int r = blockIdx.x;
    int p0 = r * RSTRIDE, p1 = rcur[r];
    h[t] = 0;
    __syncthreads();
    for (int p = p0 + t; p < p1; p += 256)
        atomicAdd(&h[pairs[p].y & 255], 1);
    __syncthreads();
    int v = h[t];
    int incl = block_incl_scan(v, ws);
    int start = p0 + incl - v;
    __syncthreads();
    h[t] = start;
    rowstart[r * 256 + t] = start;
    degv[r * 256 + t] = v;
    __syncthreads();
    for (int p = p0 + t; p < p1; p += 256) {
        int2 e = pairs[p];
        int pos = atomicAdd(&h[e.y & 255], 1);
        csr[pos] = e.x;
    }
}

// ---------------------------------------------------------------------------
// xplus = feat + mean_neighbors(feat).  fp8 gathers, f32 accum, bf16 self.
// ---------------------------------------------------------------------------
__global__ __launch_bounds__(256) void k_agg(const unsigned short* __restrict__ fb,
                                             const unsigned char* __restrict__ f8,
                                             const int* __restrict__ rowstart,
                                             const int* __restrict__ degv,
                                             const int* __restrict__ csr,
                                             unsigned short* __restrict__ xb) {
    int w = threadIdx.x >> 6, lane = threadIdx.x & 63;
    int node = blockIdx.x * 4 + w;
    int r0 = rowstart[node], dg = degv[node], r1 = r0 + dg;
    u16x8 self = *(const u16x8*)&fb[(size_t)node * D + lane * 8];
    float a[8] = {};
    for (int base = r0; base < r1; base += 64) {
        int ii = base + lane;
        int idx = N;
        if (ii < r1) idx = csr[ii];
        int cnt = r1 - base; if (cnt > 64) cnt = 64;
        int batches = (cnt + 7) & ~7;
        for (int j = 0; j < batches; j += 8) {
            int s0 = __shfl(idx, j + 0), s1 = __shfl(idx, j + 1);
            int s2 = __shfl(idx, j + 2), s3 = __shfl(idx, j + 3);
            int s4 = __shfl(idx, j + 4), s5 = __shfl(idx, j + 5);
            int s6 = __shfl(idx, j + 6), s7 = __shfl(idx, j + 7);
            uint2 g0 = *(const uint2*)&f8[(size_t)s0 * D + lane * 8];
            uint2 g1 = *(const uint2*)&f8[(size_t)s1 * D + lane * 8];
            uint2 g2 = *(const uint2*)&f8[(size_t)s2 * D + lane * 8];
            uint2 g3 = *(const uint2*)&f8[(size_t)s3 * D + lane * 8];
            uint2 g4 = *(const uint2*)&f8[(size_t)s4 * D + lane * 8];
            uint2 g5 = *(const uint2*)&f8[(size_t)s5 * D + lane * 8];
            uint2 g6 = *(const uint2*)&f8[(size_t)s6 * D + lane * 8];
            uint2 g7 = *(const uint2*)&f8[(size_t)s7 * D + lane * 8];
            acc8_fp8(a, g0); acc8_fp8(a, g1); acc8_fp8(a, g2); acc8_fp8(a, g3);
            acc8_fp8(a, g4); acc8_fp8(a, g5); acc8_fp8(a, g6); acc8_fp8(a, g7);
        }
    }
    float inv = 1.0f / fmaxf((float)dg, 1.0f);
    u16x8 o;
    #pragma unroll
    for (int q = 0; q < 8; ++q) o[q] = f2bf(bf2f(self[q]) + a[q] * inv);
    *(u16x8*)&xb[(size_t)node * D + lane * 8] = o;
}

// ---------------------------------------------------------------------------
// hfeat = relu(xplus @ W_feat + b) -> bf16.  MFMA 128x128 tile, 2x2 waves.
// ---------------------------------------------------------------------------
__global__ __launch_bounds__(256) void k_gemm_feat(const unsigned short* __restrict__ Xb,
                                                   const unsigned short* __restrict__ Wt,
                                                   const float* __restrict__ bias,
                                                   unsigned short* __restrict__ Hf) {
    __shared__ unsigned short As[128 * 64];
    __shared__ unsigned short Bs[128 * 64];
    int t = threadIdx.x, wid = t >> 6, lane = t & 63;
    int wm = wid >> 1, wn = wid & 1;
    int row0 = blockIdx.x * 128, col0 = blockIdx.y * 128;
    int r8 = lane >> 3, ch = (lane & 7) ^ r8;
    f32x4 acc[4][4] = {};
    for (int k0 = 0; k0 < D; k0 += 64) {
        #pragma unroll
        for (int i = 0; i < 4; ++i) {
            int rr = wid * 32 + i * 8;
            glds16(Xb + (size_t)(row0 + rr + r8) * D + k0 + ch * 8, As + rr * 64);
            glds16(Wt + (size_t)(col0 + rr + r8) * D + k0 + ch * 8, Bs + rr * 64);
        }
        __syncthreads();
        #pragma unroll
        for (int ks = 0; ks < 2; ++ks) {
            bf16x8 af[4], bfr[4];
            #pragma unroll
            for (int f = 0; f < 4; ++f) {
                int ra = wm * 64 + f * 16 + (lane & 15);
                af[f] = *(const bf16x8*)&As[ra * 64 + (((ks * 4 + (lane >> 4)) ^ (ra & 7)) << 3)];
                int rb = wn * 64 + f * 16 + (lane & 15);
                bfr[f] = *(const bf16x8*)&Bs[rb * 64 + (((ks * 4 + (lane >> 4)) ^ (rb & 7)) << 3)];
            }
            #pragma unroll
            for (int m = 0; m < 4; ++m)
                #pragma unroll
                for (int n = 0; n < 4; ++n)
                    acc[m][n] = __builtin_amdgcn_mfma_f32_16x16x32_bf16(af[m], bfr[n], acc[m][n], 0, 0, 0);
        }
        __syncthreads();
    }
    float bv[4];
    #pragma unroll
    for (int n = 0; n < 4; ++n) bv[n] = bias[col0 + wn * 64 + n * 16 + (lane & 15)];
    #pragma unroll
    for (int m = 0; m < 4; ++m)
        #pragma unroll
        for (int r = 0; r < 4; ++r) {
            int row = row0 + wm * 64 + m * 16 + (lane >> 4) * 4 + r;
            #pragma unroll
            for (int n = 0; n < 4; ++n) {
                int col = col0 + wn * 64 + n * 16 + (lane & 15);
                float v = fmaxf(acc[m][n][r] + bv[n], 0.f);
                Hf[(size_t)row * D + col] = f2bf(v);
            }
        }
}

// ---------------------------------------------------------------------------
// sc = softmax(relu(xplus @ Wp_g + b_g)) over 128 in-graph cols.
// Writes bf16 (for h) AND fp8 e4m3 scaled x16 (for adj; descaled by 1/256).
// ---------------------------------------------------------------------------
__global__ __launch_bounds__(256) void k_gemm_pool(const unsigned short* __restrict__ Xb,
                                                   const unsigned short* __restrict__ Wpt,
                                                   const float* __restrict__ bp,
                                                   unsigned short* __restrict__ sc,
                                                   unsigned char* __restrict__ sc8) {
    __shared__ unsigned short As[128 * 64];
    __shared__ unsigned short Bs[128 * 64];
    int t = threadIdx.x, wid = t >> 6, lane = t & 63;
    int bm = blockIdx.x;      // 0..31
    int g  = blockIdx.y;      // 0..15
    int row0 = g * NP + bm * 128;
    int nrows = NP - bm * 128; if (nrows > 128) nrows = 128;
    int col0 = g * KP;
    int r8 = lane >> 3, ch = (lane & 7) ^ r8;
    f32x4 acc[2][8] = {};
    for (int k0 = 0; k0 < D; k0 += 64) {
        #pragma unroll
        for (int i = 0; i < 4; ++i) {
            int rr = wid * 32 + i * 8;
            glds16(Xb + (size_t)(row0 + rr + r8) * D + k0 + ch * 8, As + rr * 64);
            glds16(Wpt + (size_t)(col0 + rr + r8) * D + k0 + ch * 8, Bs + rr * 64);
        }
        __syncthreads();
        #pragma unroll
        for (int ks = 0; ks < 2; ++ks) {
            bf16x8 af[2], bfr[8];
            #pragma unroll
            for (int m = 0; m < 2; ++m) {
                int ra = wid * 32 + m * 16 + (lane & 15);
                af[m] = *(const bf16x8*)&As[ra * 64 + (((ks * 4 + (lane >> 4)) ^ (ra & 7)) << 3)];
            }
            #pragma unroll
            for (int n = 0; n < 8; ++n) {
                int rb = n * 16 + (lane & 15);
                bfr[n] = *(const bf16x8*)&Bs[rb * 64 + (((ks * 4 + (lane >> 4)) ^ (rb & 7)) << 3)];
            }
            #pragma unroll
            for (int m = 0; m < 2; ++m)
                #pragma unroll
                for (int n = 0; n < 8; ++n)
                    acc[m][n] = __builtin_amdgcn_mfma_f32_16x16x32_bf16(af[m], bfr[n], acc[m][n], 0, 0, 0);
        }
        __syncthreads();
    }
    float bv[8];
    #pragma unroll
    for (int n = 0; n < 8; ++n) bv[n] = bp[col0 + n * 16 + (lane & 15)];
    #pragma unroll
    for (int m = 0; m < 2; ++m)
        #pragma unroll
        for (int r = 0; r < 4; ++r) {
            float v[8];
            #pragma unroll
            for (int n = 0; n < 8; ++n) v[n] = fmaxf(acc[m][n][r] + bv[n], 0.f);
            float mx = v[0];
            #pragma unroll
            for (int n = 1; n < 8; ++n) mx = fmaxf(mx, v[n]);
            #pragma unroll
            for (int off = 1; off < 16; off <<= 1) mx = fmaxf(mx, __shfl_xor(mx, off));
            float ssum = 0.f;
            #pragma unroll
            for (int n = 0; n < 8; ++n) { v[n] = __expf(v[n] - mx); ssum += v[n]; }
            #pragma unroll
            for (int off = 1; off < 16; off <<= 1) ssum += __shfl_xor(ssum, off);
            float inv = 1.0f / ssum;
            int rowl = wid * 32 + m * 16 + (lane >> 4) * 4 + r;
            if (rowl < nrows) {
                #pragma unroll
                for (int n = 0; n < 8; ++n) {
                    float sv = v[n] * inv;
                    int col = n * 16 + (lane & 15);
                    sc[(size_t)(row0 + rowl) * KP + col] = f2bf(sv);
                    sc8[(size_t)(row0 + rowl) * KP + col] = f2fp8(sv * 16.0f);
                }
            }
        }
}

// ---------------------------------------------------------------------------
// Fused k_h + k_adj dispatch (k_ha).
//  h: bf16 operands, XOR-swizzled u16 stage.  KZ_H=8 (500 nodes/tile) to
//     halve h atomic traffic vs KZ_H=16.
//  adj: fp8 operands (sc8, scaled x16), byte LDS stage, fp8 MFMA, acc/256.
//  2-tile register pipeline in both.  adj g1 XCD-pinned (1MB L2 window).
// ---------------------------------------------------------------------------
constexpr int VBASE = 4128;    // u16 index of V section (h path, byte 8256)
constexpr int VB8   = 4128;    // byte index of V section (adj fp8 path)
constexpr int ADJ_SPLIT = 4;
constexpr int KZ_H = 8;

__device__ __forceinline__ void uv_write(unsigned short* arr, int c0, int es,
                                         const u16x8& l0, const u16x8& l1,
                                         const u16x8& l2, const u16x8& l3) {
    #pragma unroll
    for (int q = 0; q < 8; ++q) {
        int r0 = c0 + q, r1 = c0 + 8 + q, r2 = c0 + 16 + q, r3 = c0 + 24 + q;
        arr[r0 * 32 + (es ^ (((r0 >> 1) & 3) << 3))] = l0[q];
        arr[r1 * 32 + (es ^ (((r1 >> 1) & 3) << 3))] = l1[q];
        arr[r2 * 32 + (es ^ (((r2 >> 1) & 3) << 3))] = l2[q];
        arr[r3 * 32 + (es ^ (((r3 >> 1) & 3) << 3))] = l3[q];
    }
}

__device__ __forceinline__ void row_load(const unsigned short* row,
                                         u16x8& l0, u16x8& l1, u16x8& l2, u16x8& l3) {
    l0 = *(const u16x8*)(row);
    l1 = *(const u16x8*)(row + 8);
    l2 = *(const u16x8*)(row + 16);
    l3 = *(const u16x8*)(row + 24);
}

__device__ __forceinline__ bf16x8 uv_read(const unsigned short* UV, int base,
                                          int row, int chunk) {
    int c = chunk ^ ((row >> 1) & 3);
    return *(const bf16x8*)&UV[base + row * 32 + c * 8];
}

__device__ __forceinline__ void h_body(unsigned short* UV,
                                       const unsigned short* __restrict__ sc,
                                       const unsigned short* __restrict__ hf,
                                       float* __restrict__ outH,
                                       int g, int nt, int kz) {
    int t = threadIdx.x, wid = t >> 6, lane = t & 63;
    int n0 = nt * 128;
    int i0 = g * NP + kz * (NP / KZ_H), i1 = i0 + NP / KZ_H;   // 500 nodes
    int c0 = wid * 32;
    int es = lane & 31, op = lane >> 5;   // op0 = S(cluster), op1 = H(dim)
    unsigned short* arr = &UV[op * VBASE];
    f32x4 acc[2][8] = {};

    const unsigned short* baseptr = op ? (hf + n0 + c0) : (sc + c0);
    int rstride = op ? D : KP;
    auto mkrow = [&](int tbase) -> const unsigned short* {
        int nd = tbase + es;
        nd = nd < i1 ? nd : N;
        return baseptr + (size_t)nd * rstride;
    };

    u16x8 a0, a1, a2, a3, b0, b1, b2, b3;
    row_load(mkrow(i0), a0, a1, a2, a3);
    row_load(mkrow(i0 + 32), b0, b1, b2, b3);

    int ntile = (i1 - i0 + 31) >> 5;          // = 16 for 500 nodes (even)
    for (int tt = 0; tt < ntile; tt += 2) {
        __syncthreads();
        uv_write(arr, c0, es, a0, a1, a2, a3);
        __syncthreads();
        row_load(mkrow(i0 + (tt + 2) * 32), a0, a1, a2, a3);
        {
            bf16x8 af[2], bfr[8];
            #pragma unroll
            for (int m = 0; m < 2; ++m)
                af[m] = uv_read(UV, 0, wid * 32 + m * 16 + (lane & 15), lane >> 4);
            #pragma unroll
            for (int n = 0; n < 8; ++n)
                bfr[n] = uv_read(UV, VBASE, n * 16 + (lane & 15), lane >> 4);
            #pragma unroll
            for (int m = 0; m < 2; ++m)
                #pragma unroll
                for (int n = 0; n < 8; ++n)
                    acc[m][n] = __builtin_amdgcn_mfma_f32_16x16x32_bf16(af[m], bfr[n], acc[m][n], 0, 0, 0);
        }
        __syncthreads();
        uv_write(arr, c0, es, b0, b1, b2, b3);
        __syncthreads();
        row_load(mkrow(i0 + (tt + 3) * 32), b0, b1, b2, b3);
        {
            bf16x8 af[2], bfr[8];
            #pragma unroll
            for (int m = 0; m < 2; ++m)
                af[m] = uv_read(UV, 0, wid * 32 + m * 16 + (lane & 15), lane >> 4);
            #pragma unroll
            for (int n = 0; n < 8; ++n)
                bfr[n] = uv_read(UV, VBASE, n * 16 + (lane & 15), lane >> 4);
            #pragma unroll
            for (int m = 0; m < 2; ++m)
                #pragma unroll
                for (int n = 0; n < 8; ++n)
                    acc[m][n] = __builtin_amdgcn_mfma_f32_16x16x32_bf16(af[m], bfr[n], acc[m][n], 0, 0, 0);
        }
    }
    #pragma unroll
    for (int m = 0; m < 2; ++m)
        #pragma unroll
        for (int r = 0; r < 4; ++r) {
            int row = g * KP + wid * 32 + m * 16 + (lane >> 4) * 4 + r;
            #pragma unroll
            for (int n = 0; n < 8; ++n) {
                int col = n0 + n * 16 + (lane & 15);
                atomicAdd(&outH[(size_t)row * D + col], acc[m][n][r]);
            }
        }
}

// fp8 staging helpers for adj
__device__ __forceinline__ void uv_write8(unsigned char* arr, int c0, int es,
                                          const uint4& lo, const uint4& hi) {
    const unsigned* wsrc = (const unsigned*)&lo;
    const unsigned* wsrc2 = (const unsigned*)&hi;
    int eb = es & 7, ec = es >> 3;
    #pragma unroll
    for (int qi = 0; qi < 16; ++qi) {
        {
            int row = c0 + qi;
            unsigned byte = (wsrc[qi >> 2] >> ((qi & 3) * 8)) & 255u;
            arr[row * 32 + (((ec ^ ((row >> 2) & 3)) << 3) | eb)] = (unsigned char)byte;
        }
        {
            int row = c0 + 16 + qi;
            unsigned byte = (wsrc2[qi >> 2] >> ((qi & 3) * 8)) & 255u;
            arr[row * 32 + (((ec ^ ((row >> 2) & 3)) << 3) | eb)] = (unsigned char)byte;
        }
    }
}

__device__ __forceinline__ long long uv_read8(const unsigned char* UV8, int base,
                                              int row, int chunk) {
    int c = chunk ^ ((row >> 2) & 3);
    return *(const long long*)&UV8[base + row * 32 + c * 8];
}

__device__ __forceinline__ void adj_body(unsigned char* UV8,
                                         const unsigned char* __restrict__ sc8,
                                         const int2* __restrict__ bpairs,
                                         const int* __restrict__ bcur,
                                         float* __restrict__ outA,
                                         int g1, int g2, int part) {
    int t = threadIdx.x, wid = t >> 6, lane = t & 63;
    int b = g1 * B + g2;
    int e0 = b * BSTRIDE, e1 = bcur[b], cnt = e1 - e0;
    int s0 = e0 + (int)((long long)cnt * part / ADJ_SPLIT);
    int s1 = e0 + (int)((long long)cnt * (part + 1) / ADJ_SPLIT);
    int c0 = wid * 32;
    int es = lane & 31, op = lane >> 5;   // op0 = U(src), op1 = V(dst)
    unsigned char* arr = &UV8[op * VB8];
    f32x4 acc[2][8] = {};

    auto mkrow = [&](int tbase) -> const unsigned char* {
        int idx = tbase + es;
        bool v = idx < s1;
        int2 e = bpairs[v ? idx : s0];
        int node = v ? (op ? e.y : e.x) : N;
        return sc8 + (size_t)node * KP + c0;
    };

    uint4 alo, ahi, blo, bhi;
    { const unsigned char* r = mkrow(s0);      alo = *(const uint4*)r; ahi = *(const uint4*)(r + 16); }
    { const unsigned char* r = mkrow(s0 + 32); blo = *(const uint4*)r; bhi = *(const uint4*)(r + 16); }

    int ntile = (s1 - s0 + 31) >> 5;
    for (int tt = 0; tt < ntile; tt += 2) {
        __syncthreads();
        uv_write8(arr, c0, es, alo, ahi);
        __syncthreads();
        { const unsigned char* r = mkrow(s0 + (tt + 2) * 32); alo = *(const uint4*)r; ahi = *(const uint4*)(r + 16); }
        {
            long long af[2], bfr[8];
            #pragma unroll
            for (int m = 0; m < 2; ++m)
                af[m] = uv_read8(UV8, 0, wid * 32 + m * 16 + (lane & 15), lane >> 4);
            #pragma unroll
            for (int n = 0; n < 8; ++n)
                bfr[n] = uv_read8(UV8, VB8, n * 16 + (lane & 15), lane >> 4);
            #pragma unroll
            for (int m = 0; m < 2; ++m)
                #pragma unroll
                for (int n = 0; n < 8; ++n)
                    acc[m][n] = __builtin_amdgcn_mfma_f32_16x16x32_fp8_fp8(af[m], bfr[n], acc[m][n], 0, 0, 0);
        }
        __syncthreads();
        uv_write8(arr, c0, es, blo, bhi);
        __syncthreads();
        { const unsigned char* r = mkrow(s0 + (tt + 3) * 32); blo = *(const uint4*)r; bhi = *(const uint4*)(r + 16); }
        {
            long long af[2], bfr[8];
            #pragma unroll
            for (int m = 0; m < 2; ++m)
                af[m] = uv_read8(UV8, 0, wid * 32 + m * 16 + (lane & 15), lane >> 4);
            #pragma unroll
            for (int n = 0; n < 8; ++n)
                bfr[n] = uv_read8(UV8, VB8, n * 16 + (lane & 15), lane >> 4);
            #pragma unroll
            for (int m = 0; m < 2; ++m)
                #pragma unroll
                for (int n = 0; n < 8; ++n)
                    acc[m][n] = __builtin_amdgcn_mfma_f32_16x16x32_fp8_fp8(af[m], bfr[n], acc[m][n], 0, 0, 0);
        }
    }
    const float DS = 1.0f / 256.0f;   // undo the x16 scale on both operands
    #pragma unroll
    for (int m = 0; m < 2; ++m)
        #pragma unroll
        for (int r = 0; r < 4; ++r) {
            int row = g1 * KP + wid * 32 + m * 16 + (lane >> 4) * 4 + r;
            #pragma unroll
            for (int n = 0; n < 8; ++n) {
                int col = g2 * KP + n * 16 + (lane & 15);
                atomicAdd(&outA[(size_t)row * KT + col], acc[m][n][r] * DS);
            }
        }
}

// grid = 1536 blocks = 6 slabs of 256; slabs with k%3==2 run h (2 slabs =
// 512 h tiles, KZ_H=8), others adj (4 slabs = 1024 parts, ADJ_SPLIT=4).
// adj mapping (bijective): xcd = a&7, idx = a>>3; g1 = 2*xcd + (idx&1) so
// each XCD touches only 2 graphs' U rows (1MB fp8, L2-resident).
__global__ __launch_bounds__(256) void k_ha(const unsigned short* __restrict__ sc,
                                            const unsigned char* __restrict__ sc8,
                                            const unsigned short* __restrict__ hf,
                                            const int2* __restrict__ bpairs,
                                            const int* __restrict__ bcur,
                                            float* __restrict__ outH,
                                            float* __restrict__ outA) {
    __shared__ __align__(16) unsigned short UV[8224];
    int lin = blockIdx.x;
    int k = lin >> 8, rem = lin & 255;
    if (k % 3 == 2) {
        int hbase = (k / 3) * 256 + rem;          // [0,512)
        int g = hbase & 15, nt = (hbase >> 4) & 3, kz = hbase >> 6;  // kz 0..7
        h_body(UV, sc, hf, outH, g, nt, kz);
    } else {
        int adjIdx = k - (k + 1) / 3;             // 0..3
        int base = adjIdx * 256 + rem;            // [0,1024)
        int xcd = base & 7, idx = base >> 3;
        int g1 = 2 * xcd + (idx & 1);
        int g2 = (idx >> 1) & 15;
        int part = (idx >> 5) & 3;
        adj_body((unsigned char*)UV, sc8, bpairs, bcur, outA, g1, g2, part);
    }
}

// ---------------------------------------------------------------------------
extern "C" void kernel_launch(void* const* d_in, const int* in_sizes, int n_in,
                              void* d_out, int out_size, void* d_ws, size_t ws_size,
                              hipStream_t stream) {
    const float* feat   = (const float*)d_in[0];
    const float* W_feat = (const float*)d_in[1];
    const float* b_feat = (const float*)d_in[2];
    const float* W_pool = (const float*)d_in[3];
    const float* b_pool = (const float*)d_in[4];
    const int*   src    = (const int*)d_in[5];
    const int*   dst    = (const int*)d_in[6];

    char* w = (char*)d_ws;
    unsigned short* fb  = (unsigned short*)w; w += (size_t)(N + 1) * D * 2;   // feat bf16 (+zero row)
    unsigned char*  f8b = (unsigned char*)w;  w += (size_t)(N + 1) * D;       // feat fp8 (+zero row)
    unsigned short* xb  = (unsigned short*)w; w += (size_t)N * D * 2;          // xplus bf16
    unsigned short* hfb = (unsigned short*)w; w += (size_t)(N + 1) * D * 2;   // hfeat bf16 (+zero row)
    unsigned short* scb = (unsigned short*)w; w += (size_t)(N + 1) * KP * 2;  // s bf16 (+zero row)
    unsigned char*  sc8 = (unsigned char*)w;  w += (size_t)(N + 1) * KP;      // s fp8 x16 (+zero row)
    unsigned short* Wt  = (unsigned short*)w; w += (size_t)D * D * 2;          // W_feat^T
    unsigned short* Wpt = (unsigned short*)w; w += (size_t)KT * D * 2;         // W_pool^T
    int2* pairs1  = (int2*)w; w += (size_t)NR * RSTRIDE * 8;    // padded dst-range bins
    int2* bpairs  = (int2*)w; w += (size_t)256 * BSTRIDE * 8;   // padded (gs,gd) buckets
    int*  csr     = (int*)w;  w += ((size_t)NR * RSTRIDE + 64) * 4;
    int*  rowstart= (int*)w;  w += (size_t)N * 4;
    int*  degv    = (int*)w;  w += (size_t)N * 4;
    int*  rcur    = (int*)w;  w += NR * 4;
    int*  bcur    = (int*)w;  w += 256 * 4;

    hipMemsetAsync(d_out, 0, (size_t)out_size * sizeof(float), stream);

    // conversions + pad rows
    k_cvt<<<(int)(((long long)N * D) / (8 * 256)), 256, 0, stream>>>(feat, fb, f8b, (long long)N * D);
    k_zrow<<<1, 256, 0, stream>>>(fb, scb, hfb, f8b, sc8);
    dim3 gt1(D / 32, D / 32);
    k_transpose<<<gt1, 256, 0, stream>>>(W_feat, Wt, D, D);
    dim3 gt2(KT / 32, D / 32);
    k_transpose<<<gt2, 256, 0, stream>>>(W_pool, Wpt, D, KT);

    // graph structure (padded bins; single fused split pass)
    k_init<<<1, 256, 0, stream>>>(rcur, bcur);
    k_split<<<NPB, 256, 0, stream>>>(src, dst, rcur, pairs1, bcur, bpairs);
    k_part2<<<NR, 256, 0, stream>>>(pairs1, rcur, rowstart, degv, csr);

    // aggregation + GEMMs
    k_agg<<<N / 4, 256, 0, stream>>>(fb, f8b, rowstart, degv, csr, xb);
    dim3 gf(N / 128, D / 128);
    k_gemm_feat<<<gf, 256, 0, stream>>>(xb, Wt, b_feat, hfb);
    dim3 gp(32, B);
    k_gemm_pool<<<gp, 256, 0, stream>>>(xb, Wpt, b_pool, scb, sc8);

    // fused h + adj (1536 blocks: 1024 adj parts + 512 h tiles, mixed)
    k_ha<<<1536, 256, 0, stream>>>(scb, sc8, hfb, bpairs, bcur,
                                   (float*)d_out + (size_t)KT * KT, (float*)d_out);
}

// Round 16
// 386.973 us; speedup vs baseline: 1.1585x; 1.0005x over previous
//
#include <hip/hip_runtime.h>
#include <math.h>

// Problem constants (fixed by the reference)
constexpr int N  = 64000;
constexpr int E  = 1024000;
constexpr int D  = 512;
constexpr int KT = 2048;
constexpr int B  = 16;
constexpr int NP = 4000;   // nodes per graph
constexpr int KP = 128;    // clusters per graph
constexpr int NR = N / 256;        // 250 dst-ranges of 256 nodes
constexpr int EPB = 2048;          // edges per split block
constexpr int NPB = E / EPB;       // 500 split blocks
constexpr int RSTRIDE = 4608;      // padded bin stride (Poisson 4096 +8 sigma)
constexpr int BSTRIDE = 4608;      // padded bucket stride (Poisson 4000 +9.6 sigma)

typedef __attribute__((ext_vector_type(4))) float f32x4;
typedef __attribute__((ext_vector_type(2))) float f32x2;
typedef __attribute__((ext_vector_type(8))) short bf16x8;   // MFMA A/B frag (8 bf16)
typedef __attribute__((ext_vector_type(8))) unsigned short u16x8;

__device__ __forceinline__ unsigned short f2bf(float f) {
    unsigned u = __builtin_bit_cast(unsigned, f);
    return (unsigned short)((u + 0x7FFFu + ((u >> 16) & 1u)) >> 16);
}
__device__ __forceinline__ float bf2f(unsigned short h) {
    unsigned u = (unsigned)h << 16;
    return __builtin_bit_cast(float, u);
}

// ---- fp8 e4m3 (OCP) encode/decode: HW pk-cvt if available, bit-exact fallback ----
__device__ __forceinline__ unsigned char f2fp8_sw(float f) {
    unsigned u = __builtin_bit_cast(unsigned, f);
    unsigned s = u >> 31;
    float a = fabsf(f);
    if (a > 448.f) a = 448.f;
    unsigned code;
    if (a < 0.015625f) {
        code = (unsigned)rintf(a * 512.0f);
    } else {
        unsigned au = __builtin_bit_cast(unsigned, a);
        unsigned mant = au & 0x7FFFFFu;
        unsigned rnd = 0x7FFFFu + ((mant >> 20) & 1u);
        unsigned r2 = au + rnd;
        int e = (int)(r2 >> 23) - 127;
        unsigned m3 = (r2 >> 20) & 7u;
        if (e > 8) { e = 8; m3 = 7; }
        code = (unsigned)((e + 7) << 3) | m3;
    }
    return (unsigned char)(code | (s << 7));
}
__device__ __forceinline__ float fp82f_sw(unsigned b) {
    unsigned s = b >> 7, e = (b >> 3) & 15u, m = b & 7u;
    float vn = __builtin_bit_cast(float, ((e + 120u) << 23) | (m << 20));
    float vs = (float)(int)m * 0x1p-9f;
    float v = e ? vn : vs;
    return s ? -v : v;
}

__device__ __forceinline__ unsigned char f2fp8(float f) {
#if __has_builtin(__builtin_amdgcn_cvt_pk_fp8_f32)
    int w = __builtin_amdgcn_cvt_pk_fp8_f32(f, 0.f, 0, false);
    return (unsigned char)(w & 0xFF);
#else
    return f2fp8_sw(f);
#endif
}

__device__ __forceinline__ unsigned pack4_fp8(float f0, float f1, float f2, float f3) {
#if __has_builtin(__builtin_amdgcn_cvt_pk_fp8_f32)
    int w = __builtin_amdgcn_cvt_pk_fp8_f32(f0, f1, 0, false);
    w = __builtin_amdgcn_cvt_pk_fp8_f32(f2, f3, w, true);
    return (unsigned)w;
#else
    return (unsigned)f2fp8_sw(f0) | ((unsigned)f2fp8_sw(f1) << 8) |
           ((unsigned)f2fp8_sw(f2) << 16) | ((unsigned)f2fp8_sw(f3) << 24);
#endif
}

__device__ __forceinline__ void acc8_fp8(float* a, uint2 w) {
#if __has_builtin(__builtin_amdgcn_cvt_pk_f32_fp8)
    f32x2 p0 = __builtin_amdgcn_cvt_pk_f32_fp8((int)w.x, false);
    f32x2 p1 = __builtin_amdgcn_cvt_pk_f32_fp8((int)w.x, true);
    f32x2 p2 = __builtin_amdgcn_cvt_pk_f32_fp8((int)w.y, false);
    f32x2 p3 = __builtin_amdgcn_cvt_pk_f32_fp8((int)w.y, true);
    a[0] += p0.x; a[1] += p0.y; a[2] += p1.x; a[3] += p1.y;
    a[4] += p2.x; a[5] += p2.y; a[6] += p3.x; a[7] += p3.y;
#else
    #pragma unroll
    for (int q = 0; q < 4; ++q) a[q] += fp82f_sw((w.x >> (8 * q)) & 255u);
    #pragma unroll
    for (int q = 0; q < 4; ++q) a[4 + q] += fp82f_sw((w.y >> (8 * q)) & 255u);
#endif
}

// async global->LDS, 16B per lane; lds dest must be wave-uniform base
typedef const __attribute__((address_space(1))) unsigned int* gas_u32p;
typedef __attribute__((address_space(3))) unsigned int* las_u32p;
__device__ __forceinline__ void glds16(const unsigned short* g, unsigned short* l) {
    __builtin_amdgcn_global_load_lds((gas_u32p)(const void*)g, (las_u32p)(void*)l, 16, 0, 0);
}

// block-wide (256 thr) inclusive scan; ws is 4-int LDS scratch
__device__ __forceinline__ int block_incl_scan(int v, int* ws) {
    int t = threadIdx.x, lane = t & 63, w = t >> 6;
    int x = v;
    #pragma unroll
    for (int off = 1; off < 64; off <<= 1) {
        int y = __shfl_up(x, off);
        if (lane >= off) x += y;
    }
    if (lane == 63) ws[w] = x;
    __syncthreads();
    if (t < 4) {
        int s = ws[t];
        #pragma unroll
        for (int off = 1; off < 4; off <<= 1) {
            int y = __shfl_up(s, off);
            if (t >= off) s += y;
        }
        ws[t] = s;
    }
    __syncthreads();
    return x + (w > 0 ? ws[w - 1] : 0);
}

// ---------------------------------------------------------------------------
// f32 -> bf16 + fp8 dual convert (n multiple of 8)
// ---------------------------------------------------------------------------
__global__ __launch_bounds__(256) void k_cvt(const float* __restrict__ in,
                                             unsigned short* __restrict__ outb,
                                             unsigned char* __restrict__ out8,
                                             long long n) {
    long long i = ((long long)blockIdx.x * 256 + threadIdx.x) * 8;
    if (i >= n) return;
    f32x4 a = *(const f32x4*)&in[i];
    f32x4 b = *(const f32x4*)&in[i + 4];
    u16x8 o;
    o[0] = f2bf(a.x); o[1] = f2bf(a.y); o[2] = f2bf(a.z); o[3] = f2bf(a.w);
    o[4] = f2bf(b.x); o[5] = f2bf(b.y); o[6] = f2bf(b.z); o[7] = f2bf(b.w);
    *(u16x8*)&outb[i] = o;
    uint2 w;
    w.x = pack4_fp8(a.x, a.y, a.z, a.w);
    w.y = pack4_fp8(b.x, b.y, b.z, b.w);
    *(uint2*)&out8[i] = w;
}

// zero the pad rows (row index N) of fb, scb, hfb, f8b, sc8 each launch
__global__ void k_zrow(unsigned short* __restrict__ fb,
                       unsigned short* __restrict__ scb,
                       unsigned short* __restrict__ hfb,
                       unsigned char* __restrict__ f8b,
                       unsigned char* __restrict__ sc8) {
    int t = threadIdx.x;
    const u16x8 Z = {0, 0, 0, 0, 0, 0, 0, 0};
    if (t < 64)        *(u16x8*)&fb[(size_t)N * D + t * 8] = Z;
    else if (t < 80)   *(u16x8*)&scb[(size_t)N * KP + (t - 64) * 8] = Z;
    else if (t < 144)  *(u16x8*)&hfb[(size_t)N * D + (t - 80) * 8] = Z;
    else if (t < 176)  *(u16x8*)&f8b[(size_t)N * D + (size_t)(t - 144) * 16] = Z;
    else if (t < 184)  *(u16x8*)&sc8[(size_t)N * KP + (size_t)(t - 176) * 16] = Z;
}

// f32 [R][C] -> bf16 [C][R] transpose-convert
__global__ __launch_bounds__(256) void k_transpose(const float* __restrict__ in,
                                                   unsigned short* __restrict__ out,
                                                   int R, int C) {
    __shared__ float tile[32][33];
    int bx = blockIdx.x * 32, by = blockIdx.y * 32;
    int tx = threadIdx.x & 31, ty = threadIdx.x >> 5;   // ty 0..7
    #pragma unroll
    for (int i = 0; i < 32; i += 8)
        if (by + ty + i < R && bx + tx < C)
            tile[ty + i][tx] = in[(size_t)(by + ty + i) * C + bx + tx];
    __syncthreads();
    #pragma unroll
    for (int i = 0; i < 32; i += 8)
        if (bx + ty + i < C && by + tx < R)
            out[(size_t)(bx + ty + i) * R + by + tx] = f2bf(tile[tx][ty + i]);
}

// ---------------------------------------------------------------------------
// Graph build: padded bins (no counting pass) + LDS-staged coalesced writes
// ---------------------------------------------------------------------------
__global__ void k_init(int* __restrict__ rcur, int* __restrict__ bcur) {
    int t = threadIdx.x;
    if (t < NR) rcur[t] = t * RSTRIDE;
    bcur[t] = t * BSTRIDE;
}

// one pass: partition by dst>>8 into pairs1 AND by (gs,gd) into bpairs
__global__ __launch_bounds__(256) void k_split(const int* __restrict__ src,
                                               const int* __restrict__ dst,
                                               int* __restrict__ rcur, int2* __restrict__ out1,
                                               int* __restrict__ bcur, int2* __restrict__ out2) {
    __shared__ int2 stg[EPB];
    __shared__ int h[256], lstart[256], gbase[256];
    __shared__ int ws[4];
    int t = threadIdx.x;
    int e0 = blockIdx.x * EPB;
    int sv[8], dv[8], bin[8], rank[8];
    #pragma unroll
    for (int i = 0; i < 8; ++i) {
        int e = e0 + t + i * 256;
        sv[i] = src[e]; dv[i] = dst[e];
    }
    // ---- pass A: bin by dst>>8 ----
    h[t] = 0;
    __syncthreads();
    #pragma unroll
    for (int i = 0; i < 8; ++i) {
        bin[i] = dv[i] >> 8;
        rank[i] = atomicAdd(&h[bin[i]], 1);
    }
    __syncthreads();
    {
        int v = h[t];
        int incl = block_incl_scan(v, ws);
        lstart[t] = incl - v;
        gbase[t] = v ? atomicAdd(&rcur[t], v) : 0;
    }
    __syncthreads();
    #pragma unroll
    for (int i = 0; i < 8; ++i)
        stg[lstart[bin[i]] + rank[i]] = int2{sv[i], dv[i]};
    __syncthreads();
    for (int i = t; i < EPB; i += 256) {
        int2 e = stg[i];
        int b = e.y >> 8;
        out1[gbase[b] + i - lstart[b]] = e;
    }
    __syncthreads();
    // ---- pass B: bin by (gs,gd) bucket ----
    h[t] = 0;
    __syncthreads();
    #pragma unroll
    for (int i = 0; i < 8; ++i) {
        bin[i] = (sv[i] / NP) * B + dv[i] / NP;
        rank[i] = atomicAdd(&h[bin[i]], 1);
    }
    __syncthreads();
    {
        int v = h[t];
        int incl = block_incl_scan(v, ws);
        lstart[t] = incl - v;
        gbase[t] = v ? atomicAdd(&bcur[t], v) : 0;
    }
    __syncthreads();
    #pragma unroll
    for (int i = 0; i < 8; ++i)
        stg[lstart[bin[i]] + rank[i]] = int2{sv[i], dv[i]};
    __syncthreads();
    for (int i = t; i < EPB; i += 256) {
        int2 e = stg[i];
        int b = (e.x / NP) * B + e.y / NP;
        out2[gbase[b] + i - lstart[b]] = e;
    }
}

// per 256-node range: exact-dst counting sort -> rowstart + deg + csr
__global__ __launch_bounds__(256) void k_part2(const int2* __restrict__ pairs,
                                               const int* __restrict__ rcur,
                                               int* __restrict__ rowstart,
                                               int* __restrict__ degv,
                                               int* __restrict__ csr) {
    __shared__ int h[256];
    __shared__ int ws[4];
    int t = threadIdx.x;
    int r = blockIdx.x;
    int p0 = r * RSTRIDE, p1 = rcur[r];
    h[t] = 0;
    __syncthreads();
    for (int p = p0 + t; p < p1; p += 256)
        atomicAdd(&h[pairs[p].y & 255], 1);
    __syncthreads();
    int v = h[t];
    int incl = block_incl_scan(v, ws);
    int start = p0 + incl - v;
    __syncthreads();
    h[t] = start;
    rowstart[r * 256 + t] = start;
    degv[r * 256 + t] = v;
    __syncthreads();
    for (int p = p0 + t; p < p1; p += 256) {
        int2 e = pairs[p];
        int pos = atomicAdd(&h[e.y & 255], 1);
        csr[pos] = e.x;
    }
}

// ---------------------------------------------------------------------------
// xplus = feat + mean_neighbors(feat).  fp8 gathers, f32 accum, bf16 self.
// ---------------------------------------------------------------------------
__global__ __launch_bounds__(256) void k_agg(const unsigned short* __restrict__ fb,
                                             const unsigned char* __restrict__ f8,
                                             const int* __restrict__ rowstart,
                                             const int* __restrict__ degv,
                                             const int* __restrict__ csr,
                                             unsigned short* __restrict__ xb) {
    int w = threadIdx.x >> 6, lane = threadIdx.x & 63;
    int node = blockIdx.x * 4 + w;
    int r0 = rowstart[node], dg = degv[node], r1 = r0 + dg;
    u16x8 self = *(const u16x8*)&fb[(size_t)node * D + lane * 8];
    float a[8] = {};
    for (int base = r0; base < r1; base += 64) {
        int ii = base + lane;
        int idx = N;
        if (ii < r1) idx = csr[ii];
        int cnt = r1 - base; if (cnt > 64) cnt = 64;
        int batches = (cnt + 7) & ~7;
        for (int j = 0; j < batches; j += 8) {
            int s0 = __shfl(idx, j + 0), s1 = __shfl(idx, j + 1);
            int s2 = __shfl(idx, j + 2), s3 = __shfl(idx, j + 3);
            int s4 = __shfl(idx, j + 4), s5 = __shfl(idx, j + 5);
            int s6 = __shfl(idx, j + 6), s7 = __shfl(idx, j + 7);
            uint2 g0 = *(const uint2*)&f8[(size_t)s0 * D + lane * 8];
            uint2 g1 = *(const uint2*)&f8[(size_t)s1 * D + lane * 8];
            uint2 g2 = *(const uint2*)&f8[(size_t)s2 * D + lane * 8];
            uint2 g3 = *(const uint2*)&f8[(size_t)s3 * D + lane * 8];
            uint2 g4 = *(const uint2*)&f8[(size_t)s4 * D + lane * 8];
            uint2 g5 = *(const uint2*)&f8[(size_t)s5 * D + lane * 8];
            uint2 g6 = *(const uint2*)&f8[(size_t)s6 * D + lane * 8];
            uint2 g7 = *(const uint2*)&f8[(size_t)s7 * D + lane * 8];
            acc8_fp8(a, g0); acc8_fp8(a, g1); acc8_fp8(a, g2); acc8_fp8(a, g3);
            acc8_fp8(a, g4); acc8_fp8(a, g5); acc8_fp8(a, g6); acc8_fp8(a, g7);
        }
    }
    float inv = 1.0f / fmaxf((float)dg, 1.0f);
    u16x8 o;
    #pragma unroll
    for (int q = 0; q < 8; ++q) o[q] = f2bf(bf2f(self[q]) + a[q] * inv);
    *(u16x8*)&xb[(size_t)node * D + lane * 8] = o;
}

// ---------------------------------------------------------------------------
// hfeat = relu(xplus @ W_feat + b) -> bf16.  MFMA 128x128 tile, 2x2 waves.
// ---------------------------------------------------------------------------
__global__ __launch_bounds__(256) void k_gemm_feat(const unsigned short* __restrict__ Xb,
                                                   const unsigned short* __restrict__ Wt,
                                                   const float* __restrict__ bias,
                                                   unsigned short* __restrict__ Hf) {
    __shared__ unsigned short As[128 * 64];
    __shared__ unsigned short Bs[128 * 64];
    int t = threadIdx.x, wid = t >> 6, lane = t & 63;
    int wm = wid >> 1, wn = wid & 1;
    int row0 = blockIdx.x * 128, col0 = blockIdx.y * 128;
    int r8 = lane >> 3, ch = (lane & 7) ^ r8;
    f32x4 acc[4][4] = {};
    for (int k0 = 0; k0 < D; k0 += 64) {
        #pragma unroll
        for (int i = 0; i < 4; ++i) {
            int rr = wid * 32 + i * 8;
            glds16(Xb + (size_t)(row0 + rr + r8) * D + k0 + ch * 8, As + rr * 64);
            glds16(Wt + (size_t)(col0 + rr + r8) * D + k0 + ch * 8, Bs + rr * 64);
        }
        __syncthreads();
        #pragma unroll
        for (int ks = 0; ks < 2; ++ks) {
            bf16x8 af[4], bfr[4];
            #pragma unroll
            for (int f = 0; f < 4; ++f) {
                int ra = wm * 64 + f * 16 + (lane & 15);
                af[f] = *(const bf16x8*)&As[ra * 64 + (((ks * 4 + (lane >> 4)) ^ (ra & 7)) << 3)];
                int rb = wn * 64 + f * 16 + (lane & 15);
                bfr[f] = *(const bf16x8*)&Bs[rb * 64 + (((ks * 4 + (lane >> 4)) ^ (rb & 7)) << 3)];
            }
            #pragma unroll
            for (int m = 0; m < 4; ++m)
                #pragma unroll
                for (int n = 0; n < 4; ++n)
                    acc[m][n] = __builtin_amdgcn_mfma_f32_16x16x32_bf16(af[m], bfr[n], acc[m][n], 0, 0, 0);
        }
        __syncthreads();
    }
    float bv[4];
    #pragma unroll
    for (int n = 0; n < 4; ++n) bv[n] = bias[col0 + wn * 64 + n * 16 + (lane & 15)];
    #pragma unroll
    for (int m = 0; m < 4; ++m)
        #pragma unroll
        for (int r = 0; r < 4; ++r) {
            int row = row0 + wm * 64 + m * 16 + (lane >> 4) * 4 + r;
            #pragma unroll
            for (int n = 0; n < 4; ++n) {
                int col = col0 + wn * 64 + n * 16 + (lane & 15);
                float v = fmaxf(acc[m][n][r] + bv[n], 0.f);
                Hf[(size_t)row * D + col] = f2bf(v);
            }
        }
}

// ---------------------------------------------------------------------------
// sc = softmax(relu(xplus @ Wp_g + b_g)) over 128 in-graph cols.
// Writes bf16 (for h) AND fp8 e4m3 scaled x16 (for adj; descaled by 1/256).
// ---------------------------------------------------------------------------
__global__ __launch_bounds__(256) void k_gemm_pool(const unsigned short* __restrict__ Xb,
                                                   const unsigned short* __restrict__ Wpt,
                                                   const float* __restrict__ bp,
                                                   unsigned short* __restrict__ sc,
                                                   unsigned char* __restrict__ sc8) {
    __shared__ unsigned short As[128 * 64];
    __shared__ unsigned short Bs[128 * 64];
    int t = threadIdx.x, wid = t >> 6, lane = t & 63;
    int bm = blockIdx.x;      // 0..31
    int g  = blockIdx.y;      // 0..15
    int row0 = g * NP + bm * 128;
    int nrows = NP - bm * 128; if (nrows > 128) nrows = 128;
    int col0 = g * KP;
    int r8 = lane >> 3, ch = (lane & 7) ^ r8;
    f32x4 acc[2][8] = {};
    for (int k0 = 0; k0 < D; k0 += 64) {
        #pragma unroll
        for (int i = 0; i < 4; ++i) {
            int rr = wid * 32 + i * 8;
            glds16(Xb + (size_t)(row0 + rr + r8) * D + k0 + ch * 8, As + rr * 64);
            glds16(Wpt + (size_t)(col0 + rr + r8) * D + k0 + ch * 8, Bs + rr * 64);
        }
        __syncthreads();
        #pragma unroll
        for (int ks = 0; ks < 2; ++ks) {
            bf16x8 af[2], bfr[8];
            #pragma unroll
            for (int m = 0; m < 2; ++m) {
                int ra = wid * 32 + m * 16 + (lane & 15);
                af[m] = *(const bf16x8*)&As[ra * 64 + (((ks * 4 + (lane >> 4)) ^ (ra & 7)) << 3)];
            }
            #pragma unroll
            for (int n = 0; n < 8; ++n) {
                int rb = n * 16 + (lane & 15);
                bfr[n] = *(const bf16x8*)&Bs[rb * 64 + (((ks * 4 + (lane >> 4)) ^ (rb & 7)) << 3)];
            }
            #pragma unroll
            for (int m = 0; m < 2; ++m)
                #pragma unroll
                for (int n = 0; n < 8; ++n)
                    acc[m][n] = __builtin_amdgcn_mfma_f32_16x16x32_bf16(af[m], bfr[n], acc[m][n], 0, 0, 0);
        }
        __syncthreads();
    }
    float bv[8];
    #pragma unroll
    for (int n = 0; n < 8; ++n) bv[n] = bp[col0 + n * 16 + (lane & 15)];
    #pragma unroll
    for (int m = 0; m < 2; ++m)
        #pragma unroll
        for (int r = 0; r < 4; ++r) {
            float v[8];
            #pragma unroll
            for (int n = 0; n < 8; ++n) v[n] = fmaxf(acc[m][n][r] + bv[n], 0.f);
            float mx = v[0];
            #pragma unroll
            for (int n = 1; n < 8; ++n) mx = fmaxf(mx, v[n]);
            #pragma unroll
            for (int off = 1; off < 16; off <<= 1) mx = fmaxf(mx, __shfl_xor(mx, off));
            float ssum = 0.f;
            #pragma unroll
            for (int n = 0; n < 8; ++n) { v[n] = __expf(v[n] - mx); ssum += v[n]; }
            #pragma unroll
            for (int off = 1; off < 16; off <<= 1) ssum += __shfl_xor(ssum, off);
            float inv = 1.0f / ssum;
            int rowl = wid * 32 + m * 16 + (lane >> 4) * 4 + r;
            if (rowl < nrows) {
                #pragma unroll
                for (int n = 0; n < 8; ++n) {
                    float sv = v[n] * inv;
                    int col = n * 16 + (lane & 15);
                    sc[(size_t)(row0 + rowl) * KP + col] = f2bf(sv);
                    sc8[(size_t)(row0 + rowl) * KP + col] = f2fp8(sv * 16.0f);
                }
            }
        }
}

// ---------------------------------------------------------------------------
// Fused k_h + k_adj dispatch (k_ha).
//  h: bf16 operands, XOR-swizzled u16 stage.  KZ_H=4 (1000 nodes/tile).
//  adj: fp8 operands (sc8, scaled x16), byte LDS stage, fp8 MFMA, acc/256.
//      ADJ_SPLIT=2 (2000 edges/part).
//  2-tile register pipeline in both.  adj g1 XCD-pinned (1MB L2 window).
//  Atomic write traffic: adj 32MB + h 16MB (vs r15's 64+32) — r13 measured
//  ~0.5us/MB on this path.
// ---------------------------------------------------------------------------
constexpr int VBASE = 4128;    // u16 index of V section (h path, byte 8256)
constexpr int VB8   = 4128;    // byte index of V section (adj fp8 path)
constexpr int ADJ_SPLIT = 2;
constexpr int KZ_H = 4;

__device__ __forceinline__ void uv_write(unsigned short* arr, int c0, int es,
                                         const u16x8& l0, const u16x8& l1,
                                         const u16x8& l2, const u16x8& l3) {
    #pragma unroll
    for (int q = 0; q < 8; ++q) {
        int r0 = c0 + q, r1 = c0 + 8 + q, r2 = c0 + 16 + q, r3 = c0 + 24 + q;
        arr[r0 * 32 + (es ^ (((r0 >> 1) & 3) << 3))] = l0[q];
        arr[r1 * 32 + (es ^ (((r1 >> 1) & 3) << 3))] = l1[q];
        arr[r2 * 32 + (es ^ (((r2 >> 1) & 3) << 3))] = l2[q];
        arr[r3 * 32 + (es ^ (((r3 >> 1) & 3) << 3))] = l3[q];
    }
}

__device__ __forceinline__ void row_load(const unsigned short* row,
                                         u16x8& l0, u16x8& l1, u16x8& l2, u16x8& l3) {
    l0 = *(const u16x8*)(row);
    l1 = *(const u16x8*)(row + 8);
    l2 = *(const u16x8*)(row + 16);
    l3 = *(const u16x8*)(row + 24);
}

__device__ __forceinline__ bf16x8 uv_read(const unsigned short* UV, int base,
                                          int row, int chunk) {
    int c = chunk ^ ((row >> 1) & 3);
    return *(const bf16x8*)&UV[base + row * 32 + c * 8];
}

__device__ __forceinline__ void h_body(unsigned short* UV,
                                       const unsigned short* __restrict__ sc,
                                       const unsigned short* __restrict__ hf,
                                       float* __restrict__ outH,
                                       int g, int nt, int kz) {
    int t = threadIdx.x, wid = t >> 6, lane = t & 63;
    int n0 = nt * 128;
    int i0 = g * NP + kz * (NP / KZ_H), i1 = i0 + NP / KZ_H;   // 1000 nodes
    int c0 = wid * 32;
    int es = lane & 31, op = lane >> 5;   // op0 = S(cluster), op1 = H(dim)
    unsigned short* arr = &UV[op * VBASE];
    f32x4 acc[2][8] = {};

    const unsigned short* baseptr = op ? (hf + n0 + c0) : (sc + c0);
    int rstride = op ? D : KP;
    auto mkrow = [&](int tbase) -> const unsigned short* {
        int nd = tbase + es;
        nd = nd < i1 ? nd : N;
        return baseptr + (size_t)nd * rstride;
    };

    u16x8 a0, a1, a2, a3, b0, b1, b2, b3;
    row_load(mkrow(i0), a0, a1, a2, a3);
    row_load(mkrow(i0 + 32), b0, b1, b2, b3);

    int ntile = (i1 - i0 + 31) >> 5;          // = 32 for 1000 nodes (even)
    for (int tt = 0; tt < ntile; tt += 2) {
        __syncthreads();
        uv_write(arr, c0, es, a0, a1, a2, a3);
        __syncthreads();
        row_load(mkrow(i0 + (tt + 2) * 32), a0, a1, a2, a3);
        {
            bf16x8 af[2], bfr[8];
            #pragma unroll
            for (int m = 0; m < 2; ++m)
                af[m] = uv_read(UV, 0, wid * 32 + m * 16 + (lane & 15), lane >> 4);
            #pragma unroll
            for (int n = 0; n < 8; ++n)
                bfr[n] = uv_read(UV, VBASE, n * 16 + (lane & 15), lane >> 4);
            #pragma unroll
            for (int m = 0; m < 2; ++m)
                #pragma unroll
                for (int n = 0; n < 8; ++n)
                    acc[m][n] = __builtin_amdgcn_mfma_f32_16x16x32_bf16(af[m], bfr[n], acc[m][n], 0, 0, 0);
        }
        __syncthreads();
        uv_write(arr, c0, es, b0, b1, b2, b3);
        __syncthreads();
        row_load(mkrow(i0 + (tt + 3) * 32), b0, b1, b2, b3);
        {
            bf16x8 af[2], bfr[8];
            #pragma unroll
            for (int m = 0; m < 2; ++m)
                af[m] = uv_read(UV, 0, wid * 32 + m * 16 + (lane & 15), lane >> 4);
            #pragma unroll
            for (int n = 0; n < 8; ++n)
                bfr[n] = uv_read(UV, VBASE, n * 16 + (lane & 15), lane >> 4);
            #pragma unroll
            for (int m = 0; m < 2; ++m)
                #pragma unroll
                for (int n = 0; n < 8; ++n)
                    acc[m][n] = __builtin_amdgcn_mfma_f32_16x16x32_bf16(af[m], bfr[n], acc[m][n], 0, 0, 0);
        }
    }
    #pragma unroll
    for (int m = 0; m < 2; ++m)
        #pragma unroll
        for (int r = 0; r < 4; ++r) {
            int row = g * KP + wid * 32 + m * 16 + (lane >> 4) * 4 + r;
            #pragma unroll
            for (int n = 0; n < 8; ++n) {
                int col = n0 + n * 16 + (lane & 15);
                atomicAdd(&outH[(size_t)row * D + col], acc[m][n][r]);
            }
        }
}

// fp8 staging helpers for adj
__device__ __forceinline__ void uv_write8(unsigned char* arr, int c0, int es,
                                          const uint4& lo, const uint4& hi) {
    const unsigned* wsrc = (const unsigned*)&lo;
    const unsigned* wsrc2 = (const unsigned*)&hi;
    int eb = es & 7, ec = es >> 3;
    #pragma unroll
    for (int qi = 0; qi < 16; ++qi) {
        {
            int row = c0 + qi;
            unsigned byte = (wsrc[qi >> 2] >> ((qi & 3) * 8)) & 255u;
            arr[row * 32 + (((ec ^ ((row >> 2) & 3)) << 3) | eb)] = (unsigned char)byte;
        }
        {
            int row = c0 + 16 + qi;
            unsigned byte = (wsrc2[qi >> 2] >> ((qi & 3) * 8)) & 255u;
            arr[row * 32 + (((ec ^ ((row >> 2) & 3)) << 3) | eb)] = (unsigned char)byte;
        }
    }
}

__device__ __forceinline__ long long uv_read8(const unsigned char* UV8, int base,
                                              int row, int chunk) {
    int c = chunk ^ ((row >> 2) & 3);
    return *(const long long*)&UV8[base + row * 32 + c * 8];
}

__device__ __forceinline__ void adj_body(unsigned char* UV8,
                                         const unsigned char* __restrict__ sc8,
                                         const int2* __restrict__ bpairs,
                                         const int* __restrict__ bcur,
                                         float* __restrict__ outA,
                                         int g1, int g2, int part) {
    int t = threadIdx.x, wid = t >> 6, lane = t & 63;
    int b = g1 * B + g2;
    int e0 = b * BSTRIDE, e1 = bcur[b], cnt = e1 - e0;
    int s0 = e0 + (int)((long long)cnt * part / ADJ_SPLIT);
    int s1 = e0 + (int)((long long)cnt * (part + 1) / ADJ_SPLIT);
    int c0 = wid * 32;
    int es = lane & 31, op = lane >> 5;   // op0 = U(src), op1 = V(dst)
    unsigned char* arr = &UV8[op * VB8];
    f32x4 acc[2][8] = {};

    auto mkrow = [&](int tbase) -> const unsigned char* {
        int idx = tbase + es;
        bool v = idx < s1;
        int2 e = bpairs[v ? idx : s0];
        int node = v ? (op ? e.y : e.x) : N;
        return sc8 + (size_t)node * KP + c0;
    };

    uint4 alo, ahi, blo, bhi;
    { const unsigned char* r = mkrow(s0);      alo = *(const uint4*)r; ahi = *(const uint4*)(r + 16); }
    { const unsigned char* r = mkrow(s0 + 32); blo = *(const uint4*)r; bhi = *(const uint4*)(r + 16); }

    int ntile = (s1 - s0 + 31) >> 5;
    for (int tt = 0; tt < ntile; tt += 2) {
        __syncthreads();
        uv_write8(arr, c0, es, alo, ahi);
        __syncthreads();
        { const unsigned char* r = mkrow(s0 + (tt + 2) * 32); alo = *(const uint4*)r; ahi = *(const uint4*)(r + 16); }
        {
            long long af[2], bfr[8];
            #pragma unroll
            for (int m = 0; m < 2; ++m)
                af[m] = uv_read8(UV8, 0, wid * 32 + m * 16 + (lane & 15), lane >> 4);
            #pragma unroll
            for (int n = 0; n < 8; ++n)
                bfr[n] = uv_read8(UV8, VB8, n * 16 + (lane & 15), lane >> 4);
            #pragma unroll
            for (int m = 0; m < 2; ++m)
                #pragma unroll
                for (int n = 0; n < 8; ++n)
                    acc[m][n] = __builtin_amdgcn_mfma_f32_16x16x32_fp8_fp8(af[m], bfr[n], acc[m][n], 0, 0, 0);
        }
        __syncthreads();
        uv_write8(arr, c0, es, blo, bhi);
        __syncthreads();
        { const unsigned char* r = mkrow(s0 + (tt + 3) * 32); blo = *(const uint4*)r; bhi = *(const uint4*)(r + 16); }
        {
            long long af[2], bfr[8];
            #pragma unroll
            for (int m = 0; m < 2; ++m)
                af[m] = uv_read8(UV8, 0, wid * 32 + m * 16 + (lane & 15), lane >> 4);
            #pragma unroll
            for (int n = 0; n < 8; ++n)
                bfr[n] = uv_read8(UV8, VB8, n * 16 + (lane & 15), lane >> 4);
            #pragma unroll
            for (int m = 0; m < 2; ++m)
                #pragma unroll
                for (int n = 0; n < 8; ++n)
                    acc[m][n] = __builtin_amdgcn_mfma_f32_16x16x32_fp8_fp8(af[m], bfr[n], acc[m][n], 0, 0, 0);
        }
    }
    const float DS = 1.0f / 256.0f;   // undo the x16 scale on both operands
    #pragma unroll
    for (int m = 0; m < 2; ++m)
        #pragma unroll
        for (int r = 0; r < 4; ++r) {
            int row = g1 * KP + wid * 32 + m * 16 + (lane >> 4) * 4 + r;
            #pragma unroll
            for (int n = 0; n < 8; ++n) {
                int col = g2 * KP + n * 16 + (lane & 15);
                atomicAdd(&outA[(size_t)row * KT + col], acc[m][n][r] * DS);
            }
        }
}

// grid = 768 blocks = 3 slabs of 256; slab k==2 runs h (256 tiles, KZ_H=4),
// slabs k==0,1 run adj (512 parts, ADJ_SPLIT=2).
// adj mapping (bijective): base in [0,512): xcd = base&7, idx = base>>3;
// g1 = 2*xcd + (idx&1); g2 = (idx>>1)&15; part = (idx>>5)&1  -> each XCD
// touches only 2 graphs' U rows (1MB fp8, L2-resident).  Perf-only remap.
__global__ __launch_bounds__(256) void k_ha(const unsigned short* __restrict__ sc,
                                            const unsigned char* __restrict__ sc8,
                                            const unsigned short* __restrict__ hf,
                                            const int2* __restrict__ bpairs,
                                            const int* __restrict__ bcur,
                                            float* __restrict__ outH,
                                            float* __restrict__ outA) {
    __shared__ __align__(16) unsigned short UV[8224];
    int lin = blockIdx.x;
    int k = lin >> 8, rem = lin & 255;
    if (k == 2) {
        int g = rem & 15, nt = (rem >> 4) & 3, kz = rem >> 6;   // kz 0..3
        h_body(UV, sc, hf, outH, g, nt, kz);
    } else {
        int base = k * 256 + rem;            // [0,512)
        int xcd = base & 7, idx = base >> 3;
        int g1 = 2 * xcd + (idx & 1);
        int g2 = (idx >> 1) & 15;
        int part = (idx >> 5) & 1;
        adj_body((unsigned char*)UV, sc8, bpairs, bcur, outA, g1, g2, part);
    }
}

// ---------------------------------------------------------------------------
extern "C" void kernel_launch(void* const* d_in, const int* in_sizes, int n_in,
                              void* d_out, int out_size, void* d_ws, size_t ws_size,
                              hipStream_t stream) {
    const float* feat   = (const float*)d_in[0];
    const float* W_feat = (const float*)d_in[1];
    const float* b_feat = (const float*)d_in[2];
    const float* W_pool = (const float*)d_in[3];
    const float* b_pool = (const float*)d_in[4];
    const int*   src    = (const int*)d_in[5];
    const int*   dst    = (const int*)d_in[6];

    char* w = (char*)d_ws;
    unsigned short* fb  = (unsigned short*)w; w += (size_t)(N + 1) * D * 2;   // feat bf16 (+zero row)
    unsigned char*  f8b = (unsigned char*)w;  w += (size_t)(N + 1) * D;       // feat fp8 (+zero row)
    unsigned short* xb  = (unsigned short*)w; w += (size_t)N * D * 2;          // xplus bf16
    unsigned short* hfb = (unsigned short*)w; w += (size_t)(N + 1) * D * 2;   // hfeat bf16 (+zero row)
    unsigned short* scb = (unsigned short*)w; w += (size_t)(N + 1) * KP * 2;  // s bf16 (+zero row)
    unsigned char*  sc8 = (unsigned char*)w;  w += (size_t)(N + 1) * KP;      // s fp8 x16 (+zero row)
    unsigned short* Wt  = (unsigned short*)w; w += (size_t)D * D * 2;          // W_feat^T
    unsigned short* Wpt = (unsigned short*)w; w += (size_t)KT * D * 2;         // W_pool^T
    int2* pairs1  = (int2*)w; w += (size_t)NR * RSTRIDE * 8;    // padded dst-range bins
    int2* bpairs  = (int2*)w; w += (size_t)256 * BSTRIDE * 8;   // padded (gs,gd) buckets
    int*  csr     = (int*)w;  w += ((size_t)NR * RSTRIDE + 64) * 4;
    int*  rowstart= (int*)w;  w += (size_t)N * 4;
    int*  degv    = (int*)w;  w += (size_t)N * 4;
    int*  rcur    = (int*)w;  w += NR * 4;
    int*  bcur    = (int*)w;  w += 256 * 4;

    hipMemsetAsync(d_out, 0, (size_t)out_size * sizeof(float), stream);

    // conversions + pad rows
    k_cvt<<<(int)(((long long)N * D) / (8 * 256)), 256, 0, stream>>>(feat, fb, f8b, (long long)N * D);
    k_zrow<<<1, 256, 0, stream>>>(fb, scb, hfb, f8b, sc8);
    dim3 gt1(D / 32, D / 32);
    k_transpose<<<gt1, 256, 0, stream>>>(W_feat, Wt, D, D);
    dim3 gt2(KT / 32, D / 32);
    k_transpose<<<gt2, 256, 0, stream>>>(W_pool, Wpt, D, KT);

    // graph structure (padded bins; single fused split pass)
    k_init<<<1, 256, 0, stream>>>(rcur, bcur);
    k_split<<<NPB, 256, 0, stream>>>(src, dst, rcur, pairs1, bcur, bpairs);
    k_part2<<<NR, 256, 0, stream>>>(pairs1, rcur, rowstart, degv, csr);

    // aggregation + GEMMs
    k_agg<<<N / 4, 256, 0, stream>>>(fb, f8b, rowstart, degv, csr, xb);
    dim3 gf(N / 128, D / 128);
    k_gemm_feat<<<gf, 256, 0, stream>>>(xb, Wt, b_feat, hfb);
    dim3 gp(32, B);
    k_gemm_pool<<<gp, 256, 0, stream>>>(xb, Wpt, b_pool, scb, sc8);

    // fused h + adj (768 blocks: 512 adj parts + 256 h tiles, mixed)
    k_ha<<<768, 256, 0, stream>>>(scb, sc8, hfb, bpairs, bcur,
                                  (float*)d_out + (size_t)KT * KT, (float*)d_out);
}